// Round 2
// baseline (379.273 us; speedup 1.0000x reference)
//
#include <hip/hip_runtime.h>
#include <math.h>

#define BSZ 2
#define NPOINT 128
#define NPTS 8192
#define CH_F 128
#define HEAD_BINS 12
#define KCOR 64
#define MTOT (NPOINT*KCOR)   /* 8192 corners per batch */
#define NCH 16
#define CHUNK (NPTS/NCH)     /* 512 */
#define FEAT_C 131
#define MLP2_C 256

/* ---- workspace byte offsets (256-aligned), total ~23.9 MB ---- */
#define OFF_CORNERS 0u
#define OFF_REL     196608u
#define OFF_PD      393216u      /* 2*8192*16*3 f32 = 3145728 B */
#define OFF_PIX     3538944u     /* 3145728 B */
#define OFF_FEATT   6684672u     /* [2][8192][128] = 8388608 B */
#define OFF_FEAT    15073280u    /* [2][8192][131] = 8585216 B */
#define OFF_W1T     23658496u    /* 67072 B */
#define OFF_W2T     23725568u    /* 131072 B */
/* tail reuses pd region (dead after k_minterp) */
#define OFF_H2      393216u      /* [2][256][128] */
#define OFF_X0      655360u
#define OFF_X1      786432u
#define OFF_BN0     917504u
#define OFF_BN1     918528u

/* ========== k_prep: decode (blk 0) + weight transpose (blk 1..16) + feature transpose ========== */
__global__ __launch_bounds__(256) void k_prep(const float* __restrict__ cand, const float* __restrict__ offs,
                        const float* __restrict__ angc, const float* __restrict__ angr,
                        const float* __restrict__ w1, const float* __restrict__ w2,
                        const float* __restrict__ of,
                        float* __restrict__ corners, float* __restrict__ rel,
                        float* __restrict__ w1t, float* __restrict__ w2t,
                        float* __restrict__ ft)
{
    __shared__ float tile[128][65];
    int bid = blockIdx.x;
    int t = threadIdx.x;
    if (bid == 0) {
        /* ---- decode: 256 threads = 2*128 boxes ---- */
        int b = t >> 7, p = t & 127;
        int bp = b*NPOINT + p;
        const float* ac = angc + bp*HEAD_BINS;
        int best = 0; float bv = ac[0];
        #pragma unroll
        for (int j = 1; j < HEAD_BINS; ++j) { float v = ac[j]; if (v > bv) { bv = v; best = j; } }
        float ares = angr[bp*HEAD_BINS + best];
        float angle = (float)best * 0.52359877559829882f + ares;
        float heading = (angle > 3.14159265358979323f) ? (angle - 6.28318530717958647f) : angle;
        float cx = cand[bp*3+0] + offs[bp*6+0];
        float cy = cand[bp*3+1] + offs[bp*6+1];
        float cz = cand[bp*3+2] + offs[bp*6+2];
        float dl = fmaxf(offs[bp*6+3]*2.0f, 0.1f);
        float dw = fmaxf(offs[bp*6+4]*2.0f, 0.1f);
        float dh = fmaxf(offs[bp*6+5]*2.0f, 0.1f);
        float chd = cosf(heading), shd = sinf(heading);
        for (int k = 0; k < KCOR; ++k) {
            int ix = (k>>4)&3, iy = (k>>2)&3, iz = k&3;
            float gx = (ix==3) ? 1.0f : (-1.0f + (2.0f/3.0f)*(float)ix);
            float gy = (iy==3) ? 1.0f : (-1.0f + (2.0f/3.0f)*(float)iy);
            float gz = (iz==3) ? 1.0f : (-1.0f + (2.0f/3.0f)*(float)iz);
            float wx = gx*dl, wy = gy*dw, wz = gz*dh;
            float rx = wx*chd - wy*shd;
            float ry = wx*shd + wy*chd;
            size_t base = ((size_t)b*MTOT + p*KCOR + k)*3;
            rel[base+0] = rx; rel[base+1] = ry; rel[base+2] = wz;
            corners[base+0] = rx + cx; corners[base+1] = ry + cy; corners[base+2] = wz + cz;
        }
    } else if (bid <= 16) {
        int i0 = (bid-1)*256 + t;
        for (int i = i0; i < FEAT_C*128; i += 16*256) { int o = i & 127, c = i >> 7; w1t[i] = w1[o*FEAT_C + c]; }
        for (int i = i0; i < 128*256;    i += 16*256) { int o = i & 255, c = i >> 8; w2t[i] = w2[o*128 + c]; }
    } else {
        /* ---- feature transpose: 256 blocks ---- */
        int bi = bid - 17;
        int n0 = (bi >> 1) * 64;
        int b = bi & 1;
        int r = t >> 6, col = t & 63;
        for (int c = r; c < 128; c += 4)
            tile[c][col] = of[((size_t)b*CH_F + c)*NPTS + n0 + col];
        __syncthreads();
        int cw = t & 127, nb = t >> 7;
        for (int n = nb; n < 64; n += 2)
            ft[((size_t)b*NPTS + n0 + n)*CH_F + cw] = tile[cw][n];
    }
}

/* ========== three_nn partial: per-chunk top-3, 2 corners/thread ========== */
__global__ __launch_bounds__(256) void k_three_nn(const float* __restrict__ xyz,
        const float* __restrict__ corners, float* __restrict__ pd, int* __restrict__ pix)
{
    __shared__ float4 pts[CHUNK];
    int mb = blockIdx.x;   /* 0..15 : 512 corners each */
    int ch = blockIdx.y;   /* 0..15 */
    int b  = blockIdx.z;   /* 0..1  */
    int t = threadIdx.x;

    if (t < 128) {
        const float4* s4 = (const float4*)(xyz + ((size_t)b*NPTS + (size_t)ch*CHUNK)*3);
        float4 a0 = s4[t*3+0], a1 = s4[t*3+1], a2 = s4[t*3+2];
        pts[t*4+0] = make_float4(a0.x, a0.y, a0.z, (a0.x*a0.x + a0.y*a0.y) + a0.z*a0.z);
        pts[t*4+1] = make_float4(a0.w, a1.x, a1.y, (a0.w*a0.w + a1.x*a1.x) + a1.y*a1.y);
        pts[t*4+2] = make_float4(a1.z, a1.w, a2.x, (a1.z*a1.z + a1.w*a1.w) + a2.x*a2.x);
        pts[t*4+3] = make_float4(a2.y, a2.z, a2.w, (a2.y*a2.y + a2.z*a2.z) + a2.w*a2.w);
    }
    __syncthreads();

    int ma = mb*512 + t;          /* corner A */
    int mbn = ma + 256;           /* corner B */
    const float* cpa = corners + ((size_t)b*MTOT + ma)*3;
    const float* cpb = corners + ((size_t)b*MTOT + mbn)*3;
    float cxa = cpa[0], cya = cpa[1], cza = cpa[2];
    float cxb = cpb[0], cyb = cpb[1], czb = cpb[2];
    float sca = (cxa*cxa + cya*cya) + cza*cza;
    float scb = (cxb*cxb + cyb*cyb) + czb*czb;
    float s0a = 3.4e38f, s1a = 3.4e38f, s2a = 3.4e38f;
    float s0b = 3.4e38f, s1b = 3.4e38f, s2b = 3.4e38f;
    int i0a = 0, i1a = 0, i2a = 0, i0b = 0, i1b = 0, i2b = 0;
    #pragma unroll 8
    for (int n = 0; n < CHUNK; ++n) {
        float4 P = pts[n];                       /* broadcast LDS read */
        float dota = fmaf(cza, P.z, fmaf(cya, P.y, cxa*P.x));
        float d2a = (sca + P.w) - 2.0f*dota;
        float dotb = fmaf(czb, P.z, fmaf(cyb, P.y, cxb*P.x));
        float d2b = (scb + P.w) - 2.0f*dotb;
        /* strict <: ties keep lower (earlier) index */
        bool a0_ = d2a < s0a, a1_ = d2a < s1a, a2_ = d2a < s2a;
        i2a = a1_ ? i1a : (a2_ ? n : i2a);
        i1a = a0_ ? i0a : (a1_ ? n : i1a);
        i0a = a0_ ? n : i0a;
        s2a = __builtin_amdgcn_fmed3f(d2a, s1a, s2a);
        s1a = __builtin_amdgcn_fmed3f(d2a, s0a, s1a);
        s0a = fminf(d2a, s0a);
        bool b0_ = d2b < s0b, b1_ = d2b < s1b, b2_ = d2b < s2b;
        i2b = b1_ ? i1b : (b2_ ? n : i2b);
        i1b = b0_ ? i0b : (b1_ ? n : i1b);
        i0b = b0_ ? n : i0b;
        s2b = __builtin_amdgcn_fmed3f(d2b, s1b, s2b);
        s1b = __builtin_amdgcn_fmed3f(d2b, s0b, s1b);
        s0b = fminf(d2b, s0b);
    }
    int nb = ch*CHUNK;
    size_t oba = (((size_t)b*MTOT + ma)*NCH + ch)*3;
    pd[oba+0] = s0a; pd[oba+1] = s1a; pd[oba+2] = s2a;
    pix[oba+0] = nb+i0a; pix[oba+1] = nb+i1a; pix[oba+2] = nb+i2a;
    size_t obb = (((size_t)b*MTOT + mbn)*NCH + ch)*3;
    pd[obb+0] = s0b; pd[obb+1] = s1b; pd[obb+2] = s2b;
    pix[obb+0] = nb+i0b; pix[obb+1] = nb+i1b; pix[obb+2] = nb+i2b;
}

/* ========== merge partials + weights + feature interp (fused) ========== */
__global__ __launch_bounds__(256) void k_minterp(const float* __restrict__ xyz, const float* __restrict__ corners,
                          const float* __restrict__ pd, const int* __restrict__ pix,
                          const float* __restrict__ featT, const float* __restrict__ rel,
                          float* __restrict__ feat)
{
    __shared__ int   si[2][3];
    __shared__ float sw[2][3];
    int t = threadIdx.x;
    int cc = t >> 7, c = t & 127;
    int g = blockIdx.x*2 + cc;          /* 0..16383 */
    int b = g >> 13;
    if (c == 0) {
        float s0=3.4e38f, s1=3.4e38f, s2=3.4e38f;
        int i0=0x7fffffff, i1=0x7fffffff, i2=0x7fffffff;
        size_t base = (size_t)g * (NCH*3);
        for (int k = 0; k < NCH*3; ++k) {
            float d = pd[base+k]; int id = pix[base+k];
            bool lt0 = (d < s0) || (d == s0 && id < i0);
            bool lt1 = (d < s1) || (d == s1 && id < i1);
            bool lt2 = (d < s2) || (d == s2 && id < i2);
            s2 = lt1 ? s1 : (lt2 ? d  : s2); i2 = lt1 ? i1 : (lt2 ? id : i2);
            s1 = lt0 ? s0 : (lt1 ? d  : s1); i1 = lt0 ? i0 : (lt1 ? id : i1);
            s0 = lt0 ? d  : s0;              i0 = lt0 ? id : i0;
        }
        float cx = corners[(size_t)g*3+0], cy = corners[(size_t)g*3+1], cz = corners[(size_t)g*3+2];
        int ii[3] = {i0, i1, i2};
        float w[3];
        #pragma unroll
        for (int j = 0; j < 3; ++j) {
            const float* pp = xyz + ((size_t)b*NPTS + ii[j])*3;
            float dx = pp[0]-cx, dy = pp[1]-cy, dz = pp[2]-cz;
            float dist = sqrtf((dx*dx + dy*dy) + dz*dz);
            w[j] = 1.0f/(dist + 1e-8f);
        }
        float wsum = (w[0]+w[1])+w[2];
        #pragma unroll
        for (int j = 0; j < 3; ++j) { si[cc][j] = ii[j]; sw[cc][j] = w[j]/wsum; }
    }
    __syncthreads();
    int j0 = si[cc][0], j1 = si[cc][1], j2 = si[cc][2];
    float w0 = sw[cc][0], w1 = sw[cc][1], w2 = sw[cc][2];
    const float* fb = featT + (size_t)b*NPTS*CH_F;
    float v = (fb[(size_t)j0*CH_F + c]*w0 + fb[(size_t)j1*CH_F + c]*w1) + fb[(size_t)j2*CH_F + c]*w2;
    float* fr = feat + (size_t)g*FEAT_C;
    fr[3+c] = v;
    if (c < 3) fr[c] = rel[(size_t)g*3 + c];
}

/* ========== fused MLP1 -> MLP2 -> maxpool(K) per (b,p), 512 threads ========== */
__global__ __launch_bounds__(512) void k_mlp(const float* __restrict__ feat,
        const float* __restrict__ w1t, const float* __restrict__ b1,
        const float* __restrict__ w2t, const float* __restrict__ b2,
        float* __restrict__ h2max)
{
    __shared__ float lds[FEAT_C*64];          /* 33.5 KB, reused for h1 [128][64] */
    int blk = blockIdx.x; int b = blk >> 7, p = blk & 127;
    int t = threadIdx.x;

    const float4* src = (const float4*)(feat + (((size_t)b*MTOT) + (size_t)p*64)*FEAT_C);
    for (int i = t; i < (FEAT_C*64)/4; i += 512) {
        float4 v = src[i];
        int fl = i*4;
        #pragma unroll
        for (int j = 0; j < 4; ++j) {
            float vv = (j==0) ? v.x : (j==1) ? v.y : (j==2) ? v.z : v.w;
            int f2 = fl + j;
            int mm = f2 / FEAT_C;
            int ccx = f2 - mm*FEAT_C;
            lds[ccx*64 + mm] = vv;            /* store transposed: [c][m] */
        }
    }
    __syncthreads();

    /* phase1: o = og*4+i (32 og), m = mg*4+j (16 mg) */
    int og = t >> 4, mg = t & 15;
    float acc[4][4];
    #pragma unroll
    for (int i = 0; i < 4; ++i) { float bb = b1[og*4+i];
        #pragma unroll
        for (int j = 0; j < 4; ++j) acc[i][j] = bb; }
    #pragma unroll 4
    for (int c = 0; c < FEAT_C; ++c) {
        float4 wv = *(const float4*)(w1t + c*128 + og*4);
        float4 f0 = *(const float4*)(&lds[c*64 + mg*4]);
        float fv[4] = {f0.x,f0.y,f0.z,f0.w};
        float wa[4] = {wv.x,wv.y,wv.z,wv.w};
        #pragma unroll
        for (int i = 0; i < 4; ++i)
            #pragma unroll
            for (int j = 0; j < 4; ++j)
                acc[i][j] = fmaf(wa[i], fv[j], acc[i][j]);
    }
    __syncthreads();
    #pragma unroll
    for (int i = 0; i < 4; ++i) {
        float4 r0 = make_float4(fmaxf(acc[i][0],0.f), fmaxf(acc[i][1],0.f), fmaxf(acc[i][2],0.f), fmaxf(acc[i][3],0.f));
        *(float4*)(&lds[(og*4+i)*64 + mg*4]) = r0;
    }
    __syncthreads();

    /* phase2: o = og2*4+i (64 og2), m = mg2*8+j (8 mg2) */
    int og2 = t >> 3, mg2 = t & 7;
    float a2[4][8];
    #pragma unroll
    for (int i = 0; i < 4; ++i) { float bb = b2[og2*4+i];
        #pragma unroll
        for (int j = 0; j < 8; ++j) a2[i][j] = bb; }
    #pragma unroll 2
    for (int c = 0; c < 128; ++c) {
        float4 wv = *(const float4*)(w2t + c*MLP2_C + og2*4);
        float4 f0 = *(const float4*)(&lds[c*64 + mg2*8]);
        float4 f1 = *(const float4*)(&lds[c*64 + mg2*8 + 4]);
        float fv[8] = {f0.x,f0.y,f0.z,f0.w,f1.x,f1.y,f1.z,f1.w};
        float wa[4] = {wv.x,wv.y,wv.z,wv.w};
        #pragma unroll
        for (int i = 0; i < 4; ++i)
            #pragma unroll
            for (int j = 0; j < 8; ++j)
                a2[i][j] = fmaf(wa[i], fv[j], a2[i][j]);
    }
    float mx[4];
    #pragma unroll
    for (int i = 0; i < 4; ++i) {
        float m0 = a2[i][0];
        #pragma unroll
        for (int j = 1; j < 8; ++j) m0 = fmaxf(m0, a2[i][j]);
        mx[i] = fmaxf(m0, 0.0f);
    }
    #pragma unroll
    for (int off = 1; off < 8; off <<= 1)
        #pragma unroll
        for (int i = 0; i < 4; ++i)
            mx[i] = fmaxf(mx[i], __shfl_xor(mx[i], off, 64));
    if (mg2 == 0) {
        #pragma unroll
        for (int i = 0; i < 4; ++i)
            h2max[((size_t)b*MLP2_C + og2*4 + i)*NPOINT + p] = mx[i];
    }
}

/* ========== IoU head ========== */
__global__ void k_gemm0(const float* __restrict__ h2, const float* __restrict__ w0,
                        const float* __restrict__ b0, float* __restrict__ x0)
{
    int f = blockIdx.x*256 + threadIdx.x;
    int b = f >> 14, o = (f >> 7) & 127, p = f & 127;
    const float* hb = h2 + (size_t)b*MLP2_C*NPOINT + p;
    const float* wr = w0 + o*MLP2_C;
    float acc = b0[o];
    #pragma unroll 4
    for (int c = 0; c < MLP2_C; ++c) acc = fmaf(wr[c], hb[(size_t)c*NPOINT], acc);
    x0[f] = acc;
}

__global__ void k_bnstats(const float* __restrict__ x, const float* __restrict__ g,
                          const float* __restrict__ be, float* __restrict__ sc_sh)
{
    __shared__ float ssum[256], ssq[256];
    int t = threadIdx.x;            /* 256 */
    int o = t & 127, h = t >> 7;
    const float* xp = x + ((size_t)h*128 + o)*NPOINT;
    float s = 0.f, ss = 0.f;
    #pragma unroll 4
    for (int p = 0; p < NPOINT; ++p) { float v = xp[p]; s += v; ss += v*v; }
    ssum[t] = s; ssq[t] = ss;
    __syncthreads();
    if (t < 128) {
        s = ssum[t] + ssum[t+128]; ss = ssq[t] + ssq[t+128];
        float mean = s * (1.0f/256.0f);
        float var  = ss * (1.0f/256.0f) - mean*mean;
        if (var < 0.f) var = 0.f;
        float scale = g[t] / sqrtf(var + 1e-5f);
        sc_sh[t]       = scale;
        sc_sh[128 + t] = be[t] - mean*scale;
    }
}

__global__ void k_gemm1(const float* __restrict__ x0, const float* __restrict__ bn0,
                        const float* __restrict__ w1, const float* __restrict__ b1,
                        float* __restrict__ x1)
{
    int f = blockIdx.x*256 + threadIdx.x;
    int b = f >> 14, o = (f >> 7) & 127, p = f & 127;
    const float* xb = x0 + (size_t)b*128*NPOINT + p;
    const float* wr = w1 + o*128;
    float acc = b1[o];
    #pragma unroll 4
    for (int c = 0; c < 128; ++c) {
        float v = fmaxf(fmaf(xb[(size_t)c*NPOINT], bn0[c], bn0[128+c]), 0.0f);
        acc = fmaf(wr[c], v, acc);
    }
    x1[f] = acc;
}

__global__ void k_final(const float* __restrict__ x1, const float* __restrict__ bn1,
                        const float* __restrict__ w2, const float* __restrict__ b2,
                        float* __restrict__ out)
{
    int t = threadIdx.x;  /* 256 */
    int b = t >> 7, p = t & 127;
    float acc = b2[0];
    #pragma unroll 4
    for (int c = 0; c < 128; ++c) {
        float v = fmaxf(fmaf(x1[((size_t)b*128 + c)*NPOINT + p], bn1[c], bn1[128+c]), 0.0f);
        acc = fmaf(w2[c], v, acc);
    }
    out[b*NPOINT + p] = acc;
}

extern "C" void kernel_launch(void* const* d_in, const int* in_sizes, int n_in,
                              void* d_out, int out_size, void* d_ws, size_t ws_size,
                              hipStream_t stream)
{
    const float* xyz   = (const float*)d_in[0];
    const float* ofeat = (const float*)d_in[1];
    const float* cand  = (const float*)d_in[2];
    /* d_in[3] = pred_cls, unused */
    const float* offs  = (const float*)d_in[4];
    const float* angc  = (const float*)d_in[5];
    const float* angr  = (const float*)d_in[6];
    const float* w1    = (const float*)d_in[7];
    const float* b1    = (const float*)d_in[8];
    const float* w2    = (const float*)d_in[9];
    const float* b2    = (const float*)d_in[10];
    const float* wi0   = (const float*)d_in[11];
    const float* bi0   = (const float*)d_in[12];
    const float* gi0   = (const float*)d_in[13];
    const float* bei0  = (const float*)d_in[14];
    const float* wi1   = (const float*)d_in[15];
    const float* bi1   = (const float*)d_in[16];
    const float* gi1   = (const float*)d_in[17];
    const float* bei1  = (const float*)d_in[18];
    const float* wi2   = (const float*)d_in[19];
    const float* bi2   = (const float*)d_in[20];

    char* ws = (char*)d_ws;
    float* corners = (float*)(ws + OFF_CORNERS);
    float* rel     = (float*)(ws + OFF_REL);
    float* pd      = (float*)(ws + OFF_PD);
    int*   pix     = (int*)  (ws + OFF_PIX);
    float* featT   = (float*)(ws + OFF_FEATT);
    float* feat    = (float*)(ws + OFF_FEAT);
    float* w1t     = (float*)(ws + OFF_W1T);
    float* w2t     = (float*)(ws + OFF_W2T);
    float* h2      = (float*)(ws + OFF_H2);
    float* x0      = (float*)(ws + OFF_X0);
    float* x1      = (float*)(ws + OFF_X1);
    float* bn0     = (float*)(ws + OFF_BN0);
    float* bn1     = (float*)(ws + OFF_BN1);

    k_prep     <<<273, 256, 0, stream>>>(cand, offs, angc, angr, w1, w2, ofeat,
                                         corners, rel, w1t, w2t, featT);
    k_three_nn <<<dim3(16,16,2), 256, 0, stream>>>(xyz, corners, pd, pix);
    k_minterp  <<<8192, 256, 0, stream>>>(xyz, corners, pd, pix, featT, rel, feat);
    k_mlp      <<<256, 512, 0, stream>>>(feat, w1t, b1, w2t, b2, h2);
    k_gemm0    <<<128, 256, 0, stream>>>(h2, wi0, bi0, x0);
    k_bnstats  <<<1, 256, 0, stream>>>(x0, gi0, bei0, bn0);
    k_gemm1    <<<128, 256, 0, stream>>>(x0, bn0, wi1, bi1, x1);
    k_bnstats  <<<1, 256, 0, stream>>>(x1, gi1, bei1, bn1);
    k_final    <<<1, 256, 0, stream>>>(x1, bn1, wi2, bi2, (float*)d_out);
}

// Round 4
// 329.224 us; speedup vs baseline: 1.1520x; 1.1520x over previous
//
#include <hip/hip_runtime.h>
#include <math.h>

#define BSZ 2
#define NPOINT 128
#define NPTS 8192
#define CH_F 128
#define HEAD_BINS 12
#define KCOR 64
#define MTOT (NPOINT*KCOR)   /* 8192 corners per batch */
#define NCH 16
#define CHUNK (NPTS/NCH)     /* 512 */
#define FEAT_C 131
#define MLP2_C 256

/* ---- workspace byte offsets (256-aligned), total ~23.9 MB ---- */
#define OFF_CORNERS 0u
#define OFF_REL     196608u
#define OFF_PD      393216u      /* 2*8192*16*3 f32 = 3145728 B */
#define OFF_PIX     3538944u     /* 3145728 B */
#define OFF_FEATT   6684672u     /* [2][8192][128] = 8388608 B */
#define OFF_FEAT    15073280u    /* [2][8192][131] = 8585216 B */
#define OFF_W1T     23658496u    /* 67072 B */
#define OFF_W2T     23725568u    /* 131072 B */
/* tail reuses pd region (dead after k_minterp) */
#define OFF_H2      393216u      /* [2][256][128] */
#define OFF_X0      655360u      /* [2][128][128] */
#define OFF_X1      786432u
#define OFF_BN0     917504u      /* scale[128], shift[128] */
#define OFF_BN1     918528u

/* ========== k_prep: decode (blk 0) + weight transpose (blk 1..16) + feature transpose ========== */
__global__ __launch_bounds__(256) void k_prep(const float* __restrict__ cand, const float* __restrict__ offs,
                        const float* __restrict__ angc, const float* __restrict__ angr,
                        const float* __restrict__ w1, const float* __restrict__ w2,
                        const float* __restrict__ of,
                        float* __restrict__ corners, float* __restrict__ rel,
                        float* __restrict__ w1t, float* __restrict__ w2t,
                        float* __restrict__ ft)
{
    __shared__ float tile[128][65];
    int bid = blockIdx.x;
    int t = threadIdx.x;
    if (bid == 0) {
        int b = t >> 7, p = t & 127;
        int bp = b*NPOINT + p;
        const float* ac = angc + bp*HEAD_BINS;
        int best = 0; float bv = ac[0];
        #pragma unroll
        for (int j = 1; j < HEAD_BINS; ++j) { float v = ac[j]; if (v > bv) { bv = v; best = j; } }
        float ares = angr[bp*HEAD_BINS + best];
        float angle = (float)best * 0.52359877559829882f + ares;
        float heading = (angle > 3.14159265358979323f) ? (angle - 6.28318530717958647f) : angle;
        float cx = cand[bp*3+0] + offs[bp*6+0];
        float cy = cand[bp*3+1] + offs[bp*6+1];
        float cz = cand[bp*3+2] + offs[bp*6+2];
        float dl = fmaxf(offs[bp*6+3]*2.0f, 0.1f);
        float dw = fmaxf(offs[bp*6+4]*2.0f, 0.1f);
        float dh = fmaxf(offs[bp*6+5]*2.0f, 0.1f);
        float chd = cosf(heading), shd = sinf(heading);
        for (int k = 0; k < KCOR; ++k) {
            int ix = (k>>4)&3, iy = (k>>2)&3, iz = k&3;
            float gx = (ix==3) ? 1.0f : (-1.0f + (2.0f/3.0f)*(float)ix);
            float gy = (iy==3) ? 1.0f : (-1.0f + (2.0f/3.0f)*(float)iy);
            float gz = (iz==3) ? 1.0f : (-1.0f + (2.0f/3.0f)*(float)iz);
            float wx = gx*dl, wy = gy*dw, wz = gz*dh;
            float rx = wx*chd - wy*shd;
            float ry = wx*shd + wy*chd;
            size_t base = ((size_t)b*MTOT + p*KCOR + k)*3;
            rel[base+0] = rx; rel[base+1] = ry; rel[base+2] = wz;
            corners[base+0] = rx + cx; corners[base+1] = ry + cy; corners[base+2] = wz + cz;
        }
    } else if (bid <= 16) {
        int i0 = (bid-1)*256 + t;
        for (int i = i0; i < FEAT_C*128; i += 16*256) { int o = i & 127, c = i >> 7; w1t[i] = w1[o*FEAT_C + c]; }
        for (int i = i0; i < 128*256;    i += 16*256) { int o = i & 255, c = i >> 8; w2t[i] = w2[o*128 + c]; }
    } else {
        int bi = bid - 17;
        int n0 = (bi >> 1) * 64;
        int b = bi & 1;
        int r = t >> 6, col = t & 63;
        for (int c = r; c < 128; c += 4)
            tile[c][col] = of[((size_t)b*CH_F + c)*NPTS + n0 + col];
        __syncthreads();
        int cw = t & 127, nb = t >> 7;
        for (int n = nb; n < 64; n += 2)
            ft[((size_t)b*NPTS + n0 + n)*CH_F + cw] = tile[cw][n];
    }
}

/* ========== three_nn partial: per-chunk top-3, 1 corner/thread, 1024 blocks ========== */
__global__ __launch_bounds__(256) void k_three_nn(const float* __restrict__ xyz,
        const float* __restrict__ corners, float* __restrict__ pd, int* __restrict__ pix)
{
    __shared__ float4 pts[CHUNK];
    int mb = blockIdx.x;   /* 0..31 : 256 corners each */
    int ch = blockIdx.y;   /* 0..15 */
    int b  = blockIdx.z;   /* 0..1  */
    int t = threadIdx.x;

    if (t < 128) {
        const float4* s4 = (const float4*)(xyz + ((size_t)b*NPTS + (size_t)ch*CHUNK)*3);
        float4 a0 = s4[t*3+0], a1 = s4[t*3+1], a2 = s4[t*3+2];
        pts[t*4+0] = make_float4(a0.x, a0.y, a0.z, (a0.x*a0.x + a0.y*a0.y) + a0.z*a0.z);
        pts[t*4+1] = make_float4(a0.w, a1.x, a1.y, (a0.w*a0.w + a1.x*a1.x) + a1.y*a1.y);
        pts[t*4+2] = make_float4(a1.z, a1.w, a2.x, (a1.z*a1.z + a1.w*a1.w) + a2.x*a2.x);
        pts[t*4+3] = make_float4(a2.y, a2.z, a2.w, (a2.y*a2.y + a2.z*a2.z) + a2.w*a2.w);
    }
    __syncthreads();

    int m = mb*256 + t;
    const float* cp = corners + ((size_t)b*MTOT + m)*3;
    float cx = cp[0], cy = cp[1], cz = cp[2];
    float sc = (cx*cx + cy*cy) + cz*cz;
    float s0 = 3.4e38f, s1 = 3.4e38f, s2 = 3.4e38f;
    int i0 = 0, i1 = 0, i2 = 0;
    #pragma unroll 8
    for (int n = 0; n < CHUNK; ++n) {
        float4 P = pts[n];                       /* broadcast LDS read */
        float dot = fmaf(cz, P.z, fmaf(cy, P.y, cx*P.x));
        float d2 = (sc + P.w) - 2.0f*dot;        /* matches ref formula */
        /* strict <: ties keep lower (earlier) index */
        bool l0 = d2 < s0, l1 = d2 < s1, l2 = d2 < s2;
        i2 = l1 ? i1 : (l2 ? n : i2);
        i1 = l0 ? i0 : (l1 ? n : i1);
        i0 = l0 ? n : i0;
        s2 = __builtin_amdgcn_fmed3f(d2, s1, s2);
        s1 = __builtin_amdgcn_fmed3f(d2, s0, s1);
        s0 = fminf(d2, s0);
    }
    int nb = ch*CHUNK;
    size_t ob = (((size_t)b*MTOT + m)*NCH + ch)*3;
    pd[ob+0] = s0; pd[ob+1] = s1; pd[ob+2] = s2;
    pix[ob+0] = nb+i0; pix[ob+1] = nb+i1; pix[ob+2] = nb+i2;
}

/* ========== merge partials (LDS-staged) + weights + feature interp ========== */
__global__ __launch_bounds__(256) void k_minterp(const float* __restrict__ xyz, const float* __restrict__ corners,
                          const float* __restrict__ pd, const int* __restrict__ pix,
                          const float* __restrict__ featT, const float* __restrict__ rel,
                          float* __restrict__ feat)
{
    __shared__ float sd[2][NCH*3];
    __shared__ int   sx[2][NCH*3];
    __shared__ int   si[2][3];
    __shared__ float sw[2][3];
    int t = threadIdx.x;
    int cc = t >> 7, c = t & 127;
    int g = blockIdx.x*2 + cc;          /* 0..16383 */
    int b = g >> 13;
    if (c < NCH*3) {
        size_t base = (size_t)g*(NCH*3) + c;
        sd[cc][c] = pd[base];
        sx[cc][c] = pix[base];
    }
    __syncthreads();
    if (c == 0) {
        float s0=3.4e38f, s1=3.4e38f, s2=3.4e38f;
        int i0=0x7fffffff, i1=0x7fffffff, i2=0x7fffffff;
        for (int k = 0; k < NCH*3; ++k) {
            float d = sd[cc][k]; int id = sx[cc][k];
            bool lt0 = (d < s0) || (d == s0 && id < i0);
            bool lt1 = (d < s1) || (d == s1 && id < i1);
            bool lt2 = (d < s2) || (d == s2 && id < i2);
            s2 = lt1 ? s1 : (lt2 ? d  : s2); i2 = lt1 ? i1 : (lt2 ? id : i2);
            s1 = lt0 ? s0 : (lt1 ? d  : s1); i1 = lt0 ? i0 : (lt1 ? id : i1);
            s0 = lt0 ? d  : s0;              i0 = lt0 ? id : i0;
        }
        float cx = corners[(size_t)g*3+0], cy = corners[(size_t)g*3+1], cz = corners[(size_t)g*3+2];
        int ii[3] = {i0, i1, i2};
        float w[3];
        #pragma unroll
        for (int j = 0; j < 3; ++j) {
            const float* pp = xyz + ((size_t)b*NPTS + ii[j])*3;
            float dx = pp[0]-cx, dy = pp[1]-cy, dz = pp[2]-cz;
            float dist = sqrtf((dx*dx + dy*dy) + dz*dz);
            w[j] = 1.0f/(dist + 1e-8f);
        }
        float wsum = (w[0]+w[1])+w[2];
        #pragma unroll
        for (int j = 0; j < 3; ++j) { si[cc][j] = ii[j]; sw[cc][j] = w[j]/wsum; }
    }
    __syncthreads();
    int j0 = si[cc][0], j1 = si[cc][1], j2 = si[cc][2];
    float w0 = sw[cc][0], w1 = sw[cc][1], w2 = sw[cc][2];
    const float* fb = featT + (size_t)b*NPTS*CH_F;
    float v = (fb[(size_t)j0*CH_F + c]*w0 + fb[(size_t)j1*CH_F + c]*w1) + fb[(size_t)j2*CH_F + c]*w2;
    float* fr = feat + (size_t)g*FEAT_C;
    fr[3+c] = v;
    if (c < 3) fr[c] = rel[(size_t)g*3 + c];
}

/* ========== fused MLP1 -> MLP2 -> maxpool(K) per (b,p), 512 threads ========== */
__global__ __launch_bounds__(512) void k_mlp(const float* __restrict__ feat,
        const float* __restrict__ w1t, const float* __restrict__ b1,
        const float* __restrict__ w2t, const float* __restrict__ b2,
        float* __restrict__ h2max)
{
    __shared__ float lds[FEAT_C*64];          /* 33.5 KB, reused for h1 [128][64] */
    int blk = blockIdx.x; int b = blk >> 7, p = blk & 127;
    int t = threadIdx.x;

    const float4* src = (const float4*)(feat + (((size_t)b*MTOT) + (size_t)p*64)*FEAT_C);
    for (int i = t; i < (FEAT_C*64)/4; i += 512) {
        float4 v = src[i];
        int fl = i*4;
        #pragma unroll
        for (int j = 0; j < 4; ++j) {
            float vv = (j==0) ? v.x : (j==1) ? v.y : (j==2) ? v.z : v.w;
            int f2 = fl + j;
            int mm = f2 / FEAT_C;
            int ccx = f2 - mm*FEAT_C;
            lds[ccx*64 + mm] = vv;            /* store transposed: [c][m] */
        }
    }
    __syncthreads();

    /* phase1: o = og*4+i (32 og), m = mg*4+j (16 mg) */
    int og = t >> 4, mg = t & 15;
    float acc[4][4];
    #pragma unroll
    for (int i = 0; i < 4; ++i) { float bb = b1[og*4+i];
        #pragma unroll
        for (int j = 0; j < 4; ++j) acc[i][j] = bb; }
    #pragma unroll 4
    for (int c = 0; c < FEAT_C; ++c) {
        float4 wv = *(const float4*)(w1t + c*128 + og*4);
        float4 f0 = *(const float4*)(&lds[c*64 + mg*4]);
        float fv[4] = {f0.x,f0.y,f0.z,f0.w};
        float wa[4] = {wv.x,wv.y,wv.z,wv.w};
        #pragma unroll
        for (int i = 0; i < 4; ++i)
            #pragma unroll
            for (int j = 0; j < 4; ++j)
                acc[i][j] = fmaf(wa[i], fv[j], acc[i][j]);
    }
    __syncthreads();
    #pragma unroll
    for (int i = 0; i < 4; ++i) {
        float4 r0 = make_float4(fmaxf(acc[i][0],0.f), fmaxf(acc[i][1],0.f), fmaxf(acc[i][2],0.f), fmaxf(acc[i][3],0.f));
        *(float4*)(&lds[(og*4+i)*64 + mg*4]) = r0;
    }
    __syncthreads();

    /* phase2: o = og2*4+i (64 og2), m = mg2*8+j (8 mg2) */
    int og2 = t >> 3, mg2 = t & 7;
    float a2[4][8];
    #pragma unroll
    for (int i = 0; i < 4; ++i) { float bb = b2[og2*4+i];
        #pragma unroll
        for (int j = 0; j < 8; ++j) a2[i][j] = bb; }
    #pragma unroll 2
    for (int c = 0; c < 128; ++c) {
        float4 wv = *(const float4*)(w2t + c*MLP2_C + og2*4);
        float4 f0 = *(const float4*)(&lds[c*64 + mg2*8]);
        float4 f1 = *(const float4*)(&lds[c*64 + mg2*8 + 4]);
        float fv[8] = {f0.x,f0.y,f0.z,f0.w,f1.x,f1.y,f1.z,f1.w};
        float wa[4] = {wv.x,wv.y,wv.z,wv.w};
        #pragma unroll
        for (int i = 0; i < 4; ++i)
            #pragma unroll
            for (int j = 0; j < 8; ++j)
                a2[i][j] = fmaf(wa[i], fv[j], a2[i][j]);
    }
    float mx[4];
    #pragma unroll
    for (int i = 0; i < 4; ++i) {
        float m0 = a2[i][0];
        #pragma unroll
        for (int j = 1; j < 8; ++j) m0 = fmaxf(m0, a2[i][j]);
        mx[i] = fmaxf(m0, 0.0f);
    }
    #pragma unroll
    for (int off = 1; off < 8; off <<= 1)
        #pragma unroll
        for (int i = 0; i < 4; ++i)
            mx[i] = fmaxf(mx[i], __shfl_xor(mx[i], off, 64));
    if (mg2 == 0) {
        #pragma unroll
        for (int i = 0; i < 4; ++i)
            h2max[((size_t)b*MLP2_C + og2*4 + i)*NPOINT + p] = mx[i];
    }
}

/* ========== IoU head: gemm + BN stats fused (block = one output channel) ========== */
__global__ __launch_bounds__(256) void k_head0(const float* __restrict__ h2, const float* __restrict__ w0,
                        const float* __restrict__ b0, const float* __restrict__ g0,
                        const float* __restrict__ be0,
                        float* __restrict__ x0, float* __restrict__ bn0)
{
    __shared__ float ssum[256], ssq[256];
    int o = blockIdx.x;            /* 0..127 */
    int t = threadIdx.x;           /* 256 = (b,p) */
    int b = t >> 7, p = t & 127;
    const float* hb = h2 + (size_t)b*MLP2_C*NPOINT + p;
    const float* wr = w0 + o*MLP2_C;
    float acc = b0[o];
    #pragma unroll 8
    for (int c = 0; c < MLP2_C; ++c) acc = fmaf(wr[c], hb[(size_t)c*NPOINT], acc);
    x0[((size_t)b*128 + o)*NPOINT + p] = acc;
    ssum[t] = acc; ssq[t] = acc*acc;
    __syncthreads();
    if (t < 128) { ssum[t] += ssum[t+128]; ssq[t] += ssq[t+128]; }
    __syncthreads();
    if (t < 64) {
        float s = ssum[t] + ssum[t+64];
        float q = ssq[t] + ssq[t+64];
        #pragma unroll
        for (int off = 32; off >= 1; off >>= 1) {
            s += __shfl_down(s, off, 64);
            q += __shfl_down(q, off, 64);
        }
        if (t == 0) {
            float mean = s * (1.0f/256.0f);
            float var  = q * (1.0f/256.0f) - mean*mean;
            if (var < 0.f) var = 0.f;
            float scale = g0[o] / sqrtf(var + 1e-5f);
            bn0[o]       = scale;
            bn0[128 + o] = be0[o] - mean*scale;
        }
    }
}

__global__ __launch_bounds__(256) void k_head1(const float* __restrict__ x0, const float* __restrict__ bn0,
                        const float* __restrict__ w1, const float* __restrict__ b1,
                        const float* __restrict__ g1, const float* __restrict__ be1,
                        float* __restrict__ x1, float* __restrict__ bn1)
{
    __shared__ float ssum[256], ssq[256];
    int o = blockIdx.x;
    int t = threadIdx.x;
    int b = t >> 7, p = t & 127;
    const float* xb = x0 + (size_t)b*128*NPOINT + p;
    const float* wr = w1 + o*128;
    float acc = b1[o];
    #pragma unroll 4
    for (int c = 0; c < 128; ++c) {
        float v = fmaxf(fmaf(xb[(size_t)c*NPOINT], bn0[c], bn0[128+c]), 0.0f);
        acc = fmaf(wr[c], v, acc);
    }
    x1[((size_t)b*128 + o)*NPOINT + p] = acc;
    ssum[t] = acc; ssq[t] = acc*acc;
    __syncthreads();
    if (t < 128) { ssum[t] += ssum[t+128]; ssq[t] += ssq[t+128]; }
    __syncthreads();
    if (t < 64) {
        float s = ssum[t] + ssum[t+64];
        float q = ssq[t] + ssq[t+64];
        #pragma unroll
        for (int off = 32; off >= 1; off >>= 1) {
            s += __shfl_down(s, off, 64);
            q += __shfl_down(q, off, 64);
        }
        if (t == 0) {
            float mean = s * (1.0f/256.0f);
            float var  = q * (1.0f/256.0f) - mean*mean;
            if (var < 0.f) var = 0.f;
            float scale = g1[o] / sqrtf(var + 1e-5f);
            bn1[o]       = scale;
            bn1[128 + o] = be1[o] - mean*scale;
        }
    }
}

__global__ void k_final(const float* __restrict__ x1, const float* __restrict__ bn1,
                        const float* __restrict__ w2, const float* __restrict__ b2,
                        float* __restrict__ out)
{
    int t = threadIdx.x;  /* 256 */
    int b = t >> 7, p = t & 127;
    float acc = b2[0];
    #pragma unroll 4
    for (int c = 0; c < 128; ++c) {
        float v = fmaxf(fmaf(x1[((size_t)b*128 + c)*NPOINT + p], bn1[c], bn1[128+c]), 0.0f);
        acc = fmaf(w2[c], v, acc);
    }
    out[b*NPOINT + p] = acc;
}

extern "C" void kernel_launch(void* const* d_in, const int* in_sizes, int n_in,
                              void* d_out, int out_size, void* d_ws, size_t ws_size,
                              hipStream_t stream)
{
    const float* xyz   = (const float*)d_in[0];
    const float* ofeat = (const float*)d_in[1];
    const float* cand  = (const float*)d_in[2];
    /* d_in[3] = pred_cls, unused */
    const float* offs  = (const float*)d_in[4];
    const float* angc  = (const float*)d_in[5];
    const float* angr  = (const float*)d_in[6];
    const float* w1    = (const float*)d_in[7];
    const float* b1    = (const float*)d_in[8];
    const float* w2    = (const float*)d_in[9];
    const float* b2    = (const float*)d_in[10];
    const float* wi0   = (const float*)d_in[11];
    const float* bi0   = (const float*)d_in[12];
    const float* gi0   = (const float*)d_in[13];
    const float* bei0  = (const float*)d_in[14];
    const float* wi1   = (const float*)d_in[15];
    const float* bi1   = (const float*)d_in[16];
    const float* gi1   = (const float*)d_in[17];
    const float* bei1  = (const float*)d_in[18];
    const float* wi2   = (const float*)d_in[19];
    const float* bi2   = (const float*)d_in[20];

    char* ws = (char*)d_ws;
    float* corners = (float*)(ws + OFF_CORNERS);
    float* rel     = (float*)(ws + OFF_REL);
    float* pd      = (float*)(ws + OFF_PD);
    int*   pix     = (int*)  (ws + OFF_PIX);
    float* featT   = (float*)(ws + OFF_FEATT);
    float* feat    = (float*)(ws + OFF_FEAT);
    float* w1t     = (float*)(ws + OFF_W1T);
    float* w2t     = (float*)(ws + OFF_W2T);
    float* h2      = (float*)(ws + OFF_H2);
    float* x0      = (float*)(ws + OFF_X0);
    float* x1      = (float*)(ws + OFF_X1);
    float* bn0     = (float*)(ws + OFF_BN0);
    float* bn1     = (float*)(ws + OFF_BN1);

    k_prep     <<<273, 256, 0, stream>>>(cand, offs, angc, angr, w1, w2, ofeat,
                                         corners, rel, w1t, w2t, featT);
    k_three_nn <<<dim3(32,16,2), 256, 0, stream>>>(xyz, corners, pd, pix);
    k_minterp  <<<8192, 256, 0, stream>>>(xyz, corners, pd, pix, featT, rel, feat);
    k_mlp      <<<256, 512, 0, stream>>>(feat, w1t, b1, w2t, b2, h2);
    k_head0    <<<128, 256, 0, stream>>>(h2, wi0, bi0, gi0, bei0, x0, bn0);
    k_head1    <<<128, 256, 0, stream>>>(x0, bn0, wi1, bi1, gi1, bei1, x1, bn1);
    k_final    <<<1, 256, 0, stream>>>(x1, bn1, wi2, bi2, (float*)d_out);
}

// Round 6
// 279.231 us; speedup vs baseline: 1.3583x; 1.1790x over previous
//
#include <hip/hip_runtime.h>
#include <math.h>

#define BSZ 2
#define NPOINT 128
#define NPTS 8192
#define CH_F 128
#define HEAD_BINS 12
#define KCOR 64
#define MTOT (NPOINT*KCOR)   /* 8192 corners per batch */
#define NCH 16
#define CHUNK (NPTS/NCH)     /* 512 */
#define FEAT_C 131
#define MLP2_C 256

/* ---- workspace byte offsets (256-aligned), total ~23.9 MB ---- */
#define OFF_CORNERS 0u
#define OFF_REL     196608u
#define OFF_PD      393216u      /* 2*8192*16*3 f32 = 3145728 B */
#define OFF_PIX     3538944u     /* 3145728 B */
#define OFF_FEATT   6684672u     /* [2][8192][128] = 8388608 B */
#define OFF_FEAT    15073280u    /* [2][8192][131] = 8585216 B */
#define OFF_W1T     23658496u    /* 67072 B */
#define OFF_W2T     23725568u    /* 131072 B */
/* tail reuses pd region (dead after k_minterp) */
#define OFF_H2      393216u      /* [2][256][128] */
#define OFF_X0      655360u      /* [2][128][128] */
#define OFF_X1      786432u
#define OFF_BN0     917504u      /* scale[128], shift[128] */
#define OFF_BN1     918528u

/* ========== k_decode: corner-parallel decode (blk 0..63) + weight transpose (blk 64..79) ========== */
__global__ __launch_bounds__(256) void k_decode(const float* __restrict__ cand, const float* __restrict__ offs,
                        const float* __restrict__ angc, const float* __restrict__ angr,
                        const float* __restrict__ w1, const float* __restrict__ w2,
                        float* __restrict__ corners, float* __restrict__ rel,
                        float* __restrict__ w1t, float* __restrict__ w2t)
{
    __shared__ float sr[4*KCOR*3];   /* rel staging, 3 KB */
    __shared__ float sc_[4*KCOR*3];  /* corners staging */
    int bid = blockIdx.x;
    int t = threadIdx.x;
    if (bid < 64) {
        int b = bid >> 5, p0 = (bid & 31) * 4;
        int lb = t >> 6, k = t & 63;
        int bp = b*NPOINT + p0 + lb;
        /* per-box decode, redundant across the 64 lanes of a box (broadcast loads) */
        const float* ac = angc + bp*HEAD_BINS;
        int best = 0; float bv = ac[0];
        #pragma unroll
        for (int j = 1; j < HEAD_BINS; ++j) { float v = ac[j]; if (v > bv) { bv = v; best = j; } }
        float ares = angr[bp*HEAD_BINS + best];
        float angle = (float)best * 0.52359877559829882f + ares;
        float heading = (angle > 3.14159265358979323f) ? (angle - 6.28318530717958647f) : angle;
        float cx = cand[bp*3+0] + offs[bp*6+0];
        float cy = cand[bp*3+1] + offs[bp*6+1];
        float cz = cand[bp*3+2] + offs[bp*6+2];
        float dl = fmaxf(offs[bp*6+3]*2.0f, 0.1f);
        float dw = fmaxf(offs[bp*6+4]*2.0f, 0.1f);
        float dh = fmaxf(offs[bp*6+5]*2.0f, 0.1f);
        float chd = cosf(heading), shd = sinf(heading);
        int ix = (k>>4)&3, iy = (k>>2)&3, iz = k&3;
        float gx = (ix==3) ? 1.0f : (-1.0f + (2.0f/3.0f)*(float)ix);
        float gy = (iy==3) ? 1.0f : (-1.0f + (2.0f/3.0f)*(float)iy);
        float gz = (iz==3) ? 1.0f : (-1.0f + (2.0f/3.0f)*(float)iz);
        float wx = gx*dl, wy = gy*dw, wz = gz*dh;
        float rx = wx*chd - wy*shd;
        float ry = wx*shd + wy*chd;
        int si = (lb*KCOR + k)*3;
        sr[si+0] = rx;      sr[si+1] = ry;      sr[si+2] = wz;
        sc_[si+0] = rx+cx;  sc_[si+1] = ry+cy;  sc_[si+2] = wz+cz;
        __syncthreads();
        /* coalesced write-back: 768 floats = 192 float4 per block */
        size_t base = ((size_t)b*MTOT + (size_t)p0*KCOR)*3;   /* float offset, %4==0 */
        if (t < 192) {
            ((float4*)(rel + base))[t]     = ((const float4*)sr)[t];
            ((float4*)(corners + base))[t] = ((const float4*)sc_)[t];
        }
    } else {
        int i0 = (bid-64)*256 + t;
        for (int i = i0; i < FEAT_C*128; i += 16*256) { int o = i & 127, c = i >> 7; w1t[i] = w1[o*FEAT_C + c]; }
        for (int i = i0; i < 128*256;    i += 16*256) { int o = i & 255, c = i >> 8; w2t[i] = w2[o*128 + c]; }
    }
}

/* ========== k_transpose: [C][N] -> [N][C], 16n x 128c tiles, float4 both sides ========== */
__global__ __launch_bounds__(256) void k_transpose(const float* __restrict__ of, float* __restrict__ ft)
{
    __shared__ float tile[128][17];
    int bi = blockIdx.x;            /* 0..1023 */
    int b = bi >> 9;
    int n0 = (bi & 511) * 16;
    int t = threadIdx.x;
    #pragma unroll
    for (int it = 0; it < 2; ++it) {
        int id = it*256 + t;        /* 0..511 */
        int c = id >> 2, q = id & 3;
        float4 v = *(const float4*)(of + ((size_t)(b*CH_F + c))*NPTS + n0 + q*4);
        tile[c][q*4+0] = v.x; tile[c][q*4+1] = v.y; tile[c][q*4+2] = v.z; tile[c][q*4+3] = v.w;
    }
    __syncthreads();
    #pragma unroll
    for (int it = 0; it < 2; ++it) {
        int id = it*256 + t;
        int n = id >> 5, cq = id & 31;
        float4 o;
        o.x = tile[cq*4+0][n]; o.y = tile[cq*4+1][n]; o.z = tile[cq*4+2][n]; o.w = tile[cq*4+3][n];
        *(float4*)(ft + ((size_t)b*NPTS + n0 + n)*CH_F + cq*4) = o;
    }
}

/* ========== three_nn partial: per-chunk top-3, 1 corner/thread, 1024 blocks ========== */
__global__ __launch_bounds__(256) void k_three_nn(const float* __restrict__ xyz,
        const float* __restrict__ corners, float* __restrict__ pd, int* __restrict__ pix)
{
    __shared__ float4 pts[CHUNK];
    int mb = blockIdx.x;   /* 0..31 : 256 corners each */
    int ch = blockIdx.y;   /* 0..15 */
    int b  = blockIdx.z;   /* 0..1  */
    int t = threadIdx.x;

    if (t < 128) {
        const float4* s4 = (const float4*)(xyz + ((size_t)b*NPTS + (size_t)ch*CHUNK)*3);
        float4 a0 = s4[t*3+0], a1 = s4[t*3+1], a2 = s4[t*3+2];
        pts[t*4+0] = make_float4(a0.x, a0.y, a0.z, (a0.x*a0.x + a0.y*a0.y) + a0.z*a0.z);
        pts[t*4+1] = make_float4(a0.w, a1.x, a1.y, (a0.w*a0.w + a1.x*a1.x) + a1.y*a1.y);
        pts[t*4+2] = make_float4(a1.z, a1.w, a2.x, (a1.z*a1.z + a1.w*a1.w) + a2.x*a2.x);
        pts[t*4+3] = make_float4(a2.y, a2.z, a2.w, (a2.y*a2.y + a2.z*a2.z) + a2.w*a2.w);
    }
    __syncthreads();

    int m = mb*256 + t;
    const float* cp = corners + ((size_t)b*MTOT + m)*3;
    float cx = cp[0], cy = cp[1], cz = cp[2];
    float sc = (cx*cx + cy*cy) + cz*cz;
    float s0 = 3.4e38f, s1 = 3.4e38f, s2 = 3.4e38f;
    int i0 = 0, i1 = 0, i2 = 0;
    #pragma unroll 8
    for (int n = 0; n < CHUNK; ++n) {
        float4 P = pts[n];                       /* broadcast LDS read */
        float dot = fmaf(cz, P.z, fmaf(cy, P.y, cx*P.x));
        float d2 = (sc + P.w) - 2.0f*dot;        /* matches ref formula */
        /* strict <: ties keep lower (earlier) index */
        bool l0 = d2 < s0, l1 = d2 < s1, l2 = d2 < s2;
        i2 = l1 ? i1 : (l2 ? n : i2);
        i1 = l0 ? i0 : (l1 ? n : i1);
        i0 = l0 ? n : i0;
        s2 = __builtin_amdgcn_fmed3f(d2, s1, s2);
        s1 = __builtin_amdgcn_fmed3f(d2, s0, s1);
        s0 = fminf(d2, s0);
    }
    int nb = ch*CHUNK;
    size_t ob = (((size_t)b*MTOT + m)*NCH + ch)*3;
    pd[ob+0] = s0; pd[ob+1] = s1; pd[ob+2] = s2;
    pix[ob+0] = nb+i0; pix[ob+1] = nb+i1; pix[ob+2] = nb+i2;
}

/* ========== merge partials (LDS-staged) + weights + feature interp ========== */
__global__ __launch_bounds__(256) void k_minterp(const float* __restrict__ xyz, const float* __restrict__ corners,
                          const float* __restrict__ pd, const int* __restrict__ pix,
                          const float* __restrict__ featT, const float* __restrict__ rel,
                          float* __restrict__ feat)
{
    __shared__ float sd[2][NCH*3];
    __shared__ int   sx[2][NCH*3];
    __shared__ int   si[2][3];
    __shared__ float sw[2][3];
    int t = threadIdx.x;
    int cc = t >> 7, c = t & 127;
    int g = blockIdx.x*2 + cc;          /* 0..16383 */
    int b = g >> 13;
    if (c < NCH*3) {
        size_t base = (size_t)g*(NCH*3) + c;
        sd[cc][c] = pd[base];
        sx[cc][c] = pix[base];
    }
    __syncthreads();
    if (c == 0) {
        float s0=3.4e38f, s1=3.4e38f, s2=3.4e38f;
        int i0=0x7fffffff, i1=0x7fffffff, i2=0x7fffffff;
        for (int k = 0; k < NCH*3; ++k) {
            float d = sd[cc][k]; int id = sx[cc][k];
            bool lt0 = (d < s0) || (d == s0 && id < i0);
            bool lt1 = (d < s1) || (d == s1 && id < i1);
            bool lt2 = (d < s2) || (d == s2 && id < i2);
            s2 = lt1 ? s1 : (lt2 ? d  : s2); i2 = lt1 ? i1 : (lt2 ? id : i2);
            s1 = lt0 ? s0 : (lt1 ? d  : s1); i1 = lt0 ? i0 : (lt1 ? id : i1);
            s0 = lt0 ? d  : s0;              i0 = lt0 ? id : i0;
        }
        float cx = corners[(size_t)g*3+0], cy = corners[(size_t)g*3+1], cz = corners[(size_t)g*3+2];
        int ii[3] = {i0, i1, i2};
        float w[3];
        #pragma unroll
        for (int j = 0; j < 3; ++j) {
            const float* pp = xyz + ((size_t)b*NPTS + ii[j])*3;
            float dx = pp[0]-cx, dy = pp[1]-cy, dz = pp[2]-cz;
            float dist = sqrtf((dx*dx + dy*dy) + dz*dz);
            w[j] = 1.0f/(dist + 1e-8f);
        }
        float wsum = (w[0]+w[1])+w[2];
        #pragma unroll
        for (int j = 0; j < 3; ++j) { si[cc][j] = ii[j]; sw[cc][j] = w[j]/wsum; }
    }
    __syncthreads();
    int j0 = si[cc][0], j1 = si[cc][1], j2 = si[cc][2];
    float w0 = sw[cc][0], w1 = sw[cc][1], w2 = sw[cc][2];
    const float* fb = featT + (size_t)b*NPTS*CH_F;
    float v = (fb[(size_t)j0*CH_F + c]*w0 + fb[(size_t)j1*CH_F + c]*w1) + fb[(size_t)j2*CH_F + c]*w2;
    float* fr = feat + (size_t)g*FEAT_C;
    fr[3+c] = v;
    if (c < 3) fr[c] = rel[(size_t)g*3 + c];
}

/* ========== fused MLP1 -> MLP2 -> maxpool(K) per (b,p), 512 threads ========== */
__global__ __launch_bounds__(512) void k_mlp(const float* __restrict__ feat,
        const float* __restrict__ w1t, const float* __restrict__ b1,
        const float* __restrict__ w2t, const float* __restrict__ b2,
        float* __restrict__ h2max)
{
    __shared__ float lds[FEAT_C*64];          /* 33.5 KB, reused for h1 [128][64] */
    int blk = blockIdx.x; int b = blk >> 7, p = blk & 127;
    int t = threadIdx.x;

    const float4* src = (const float4*)(feat + (((size_t)b*MTOT) + (size_t)p*64)*FEAT_C);
    for (int i = t; i < (FEAT_C*64)/4; i += 512) {
        float4 v = src[i];
        int fl = i*4;
        #pragma unroll
        for (int j = 0; j < 4; ++j) {
            float vv = (j==0) ? v.x : (j==1) ? v.y : (j==2) ? v.z : v.w;
            int f2 = fl + j;
            int mm = f2 / FEAT_C;
            int ccx = f2 - mm*FEAT_C;
            lds[ccx*64 + mm] = vv;            /* store transposed: [c][m] */
        }
    }
    __syncthreads();

    /* phase1: o = og*4+i (32 og), m = mg*4+j (16 mg) */
    int og = t >> 4, mg = t & 15;
    float acc[4][4];
    #pragma unroll
    for (int i = 0; i < 4; ++i) { float bb = b1[og*4+i];
        #pragma unroll
        for (int j = 0; j < 4; ++j) acc[i][j] = bb; }
    #pragma unroll 4
    for (int c = 0; c < FEAT_C; ++c) {
        float4 wv = *(const float4*)(w1t + c*128 + og*4);
        float4 f0 = *(const float4*)(&lds[c*64 + mg*4]);
        float fv[4] = {f0.x,f0.y,f0.z,f0.w};
        float wa[4] = {wv.x,wv.y,wv.z,wv.w};
        #pragma unroll
        for (int i = 0; i < 4; ++i)
            #pragma unroll
            for (int j = 0; j < 4; ++j)
                acc[i][j] = fmaf(wa[i], fv[j], acc[i][j]);
    }
    __syncthreads();
    #pragma unroll
    for (int i = 0; i < 4; ++i) {
        float4 r0 = make_float4(fmaxf(acc[i][0],0.f), fmaxf(acc[i][1],0.f), fmaxf(acc[i][2],0.f), fmaxf(acc[i][3],0.f));
        *(float4*)(&lds[(og*4+i)*64 + mg*4]) = r0;
    }
    __syncthreads();

    /* phase2: o = og2*4+i (64 og2), m = mg2*8+j (8 mg2) */
    int og2 = t >> 3, mg2 = t & 7;
    float a2[4][8];
    #pragma unroll
    for (int i = 0; i < 4; ++i) { float bb = b2[og2*4+i];
        #pragma unroll
        for (int j = 0; j < 8; ++j) a2[i][j] = bb; }
    #pragma unroll 2
    for (int c = 0; c < 128; ++c) {
        float4 wv = *(const float4*)(w2t + c*MLP2_C + og2*4);
        float4 f0 = *(const float4*)(&lds[c*64 + mg2*8]);
        float4 f1 = *(const float4*)(&lds[c*64 + mg2*8 + 4]);
        float fv[8] = {f0.x,f0.y,f0.z,f0.w,f1.x,f1.y,f1.z,f1.w};
        float wa[4] = {wv.x,wv.y,wv.z,wv.w};
        #pragma unroll
        for (int i = 0; i < 4; ++i)
            #pragma unroll
            for (int j = 0; j < 8; ++j)
                a2[i][j] = fmaf(wa[i], fv[j], a2[i][j]);
    }
    float mx[4];
    #pragma unroll
    for (int i = 0; i < 4; ++i) {
        float m0 = a2[i][0];
        #pragma unroll
        for (int j = 1; j < 8; ++j) m0 = fmaxf(m0, a2[i][j]);
        mx[i] = fmaxf(m0, 0.0f);
    }
    #pragma unroll
    for (int off = 1; off < 8; off <<= 1)
        #pragma unroll
        for (int i = 0; i < 4; ++i)
            mx[i] = fmaxf(mx[i], __shfl_xor(mx[i], off, 64));
    if (mg2 == 0) {
        #pragma unroll
        for (int i = 0; i < 4; ++i)
            h2max[((size_t)b*MLP2_C + og2*4 + i)*NPOINT + p] = mx[i];
    }
}

/* ========== IoU head: gemm + BN stats fused (block = one output channel) ========== */
__global__ __launch_bounds__(256) void k_head0(const float* __restrict__ h2, const float* __restrict__ w0,
                        const float* __restrict__ b0, const float* __restrict__ g0,
                        const float* __restrict__ be0,
                        float* __restrict__ x0, float* __restrict__ bn0)
{
    __shared__ float ssum[256], ssq[256];
    int o = blockIdx.x;            /* 0..127 */
    int t = threadIdx.x;           /* 256 = (b,p) */
    int b = t >> 7, p = t & 127;
    const float* hb = h2 + (size_t)b*MLP2_C*NPOINT + p;
    const float* wr = w0 + o*MLP2_C;
    float acc = b0[o];
    #pragma unroll 8
    for (int c = 0; c < MLP2_C; ++c) acc = fmaf(wr[c], hb[(size_t)c*NPOINT], acc);
    x0[((size_t)b*128 + o)*NPOINT + p] = acc;
    ssum[t] = acc; ssq[t] = acc*acc;
    __syncthreads();
    if (t < 128) { ssum[t] += ssum[t+128]; ssq[t] += ssq[t+128]; }
    __syncthreads();
    if (t < 64) {
        float s = ssum[t] + ssum[t+64];
        float q = ssq[t] + ssq[t+64];
        #pragma unroll
        for (int off = 32; off >= 1; off >>= 1) {
            s += __shfl_down(s, off, 64);
            q += __shfl_down(q, off, 64);
        }
        if (t == 0) {
            float mean = s * (1.0f/256.0f);
            float var  = q * (1.0f/256.0f) - mean*mean;
            if (var < 0.f) var = 0.f;
            float scale = g0[o] / sqrtf(var + 1e-5f);
            bn0[o]       = scale;
            bn0[128 + o] = be0[o] - mean*scale;
        }
    }
}

__global__ __launch_bounds__(256) void k_head1(const float* __restrict__ x0, const float* __restrict__ bn0,
                        const float* __restrict__ w1, const float* __restrict__ b1,
                        const float* __restrict__ g1, const float* __restrict__ be1,
                        float* __restrict__ x1, float* __restrict__ bn1)
{
    __shared__ float ssum[256], ssq[256];
    int o = blockIdx.x;
    int t = threadIdx.x;
    int b = t >> 7, p = t & 127;
    const float* xb = x0 + (size_t)b*128*NPOINT + p;
    const float* wr = w1 + o*128;
    float acc = b1[o];
    #pragma unroll 4
    for (int c = 0; c < 128; ++c) {
        float v = fmaxf(fmaf(xb[(size_t)c*NPOINT], bn0[c], bn0[128+c]), 0.0f);
        acc = fmaf(wr[c], v, acc);
    }
    x1[((size_t)b*128 + o)*NPOINT + p] = acc;
    ssum[t] = acc; ssq[t] = acc*acc;
    __syncthreads();
    if (t < 128) { ssum[t] += ssum[t+128]; ssq[t] += ssq[t+128]; }
    __syncthreads();
    if (t < 64) {
        float s = ssum[t] + ssum[t+64];
        float q = ssq[t] + ssq[t+64];
        #pragma unroll
        for (int off = 32; off >= 1; off >>= 1) {
            s += __shfl_down(s, off, 64);
            q += __shfl_down(q, off, 64);
        }
        if (t == 0) {
            float mean = s * (1.0f/256.0f);
            float var  = q * (1.0f/256.0f) - mean*mean;
            if (var < 0.f) var = 0.f;
            float scale = g1[o] / sqrtf(var + 1e-5f);
            bn1[o]       = scale;
            bn1[128 + o] = be1[o] - mean*scale;
        }
    }
}

__global__ void k_final(const float* __restrict__ x1, const float* __restrict__ bn1,
                        const float* __restrict__ w2, const float* __restrict__ b2,
                        float* __restrict__ out)
{
    int t = threadIdx.x;  /* 256 */
    int b = t >> 7, p = t & 127;
    float acc = b2[0];
    #pragma unroll 4
    for (int c = 0; c < 128; ++c) {
        float v = fmaxf(fmaf(x1[((size_t)b*128 + c)*NPOINT + p], bn1[c], bn1[128+c]), 0.0f);
        acc = fmaf(w2[c], v, acc);
    }
    out[b*NPOINT + p] = acc;
}

extern "C" void kernel_launch(void* const* d_in, const int* in_sizes, int n_in,
                              void* d_out, int out_size, void* d_ws, size_t ws_size,
                              hipStream_t stream)
{
    const float* xyz   = (const float*)d_in[0];
    const float* ofeat = (const float*)d_in[1];
    const float* cand  = (const float*)d_in[2];
    /* d_in[3] = pred_cls, unused */
    const float* offs  = (const float*)d_in[4];
    const float* angc  = (const float*)d_in[5];
    const float* angr  = (const float*)d_in[6];
    const float* w1    = (const float*)d_in[7];
    const float* b1    = (const float*)d_in[8];
    const float* w2    = (const float*)d_in[9];
    const float* b2    = (const float*)d_in[10];
    const float* wi0   = (const float*)d_in[11];
    const float* bi0   = (const float*)d_in[12];
    const float* gi0   = (const float*)d_in[13];
    const float* bei0  = (const float*)d_in[14];
    const float* wi1   = (const float*)d_in[15];
    const float* bi1   = (const float*)d_in[16];
    const float* gi1   = (const float*)d_in[17];
    const float* bei1  = (const float*)d_in[18];
    const float* wi2   = (const float*)d_in[19];
    const float* bi2   = (const float*)d_in[20];

    char* ws = (char*)d_ws;
    float* corners = (float*)(ws + OFF_CORNERS);
    float* rel     = (float*)(ws + OFF_REL);
    float* pd      = (float*)(ws + OFF_PD);
    int*   pix     = (int*)  (ws + OFF_PIX);
    float* featT   = (float*)(ws + OFF_FEATT);
    float* feat    = (float*)(ws + OFF_FEAT);
    float* w1t     = (float*)(ws + OFF_W1T);
    float* w2t     = (float*)(ws + OFF_W2T);
    float* h2      = (float*)(ws + OFF_H2);
    float* x0      = (float*)(ws + OFF_X0);
    float* x1      = (float*)(ws + OFF_X1);
    float* bn0     = (float*)(ws + OFF_BN0);
    float* bn1     = (float*)(ws + OFF_BN1);

    k_decode   <<<80, 256, 0, stream>>>(cand, offs, angc, angr, w1, w2,
                                        corners, rel, w1t, w2t);
    k_transpose<<<1024, 256, 0, stream>>>(ofeat, featT);
    k_three_nn <<<dim3(32,16,2), 256, 0, stream>>>(xyz, corners, pd, pix);
    k_minterp  <<<8192, 256, 0, stream>>>(xyz, corners, pd, pix, featT, rel, feat);
    k_mlp      <<<256, 512, 0, stream>>>(feat, w1t, b1, w2t, b2, h2);
    k_head0    <<<128, 256, 0, stream>>>(h2, wi0, bi0, gi0, bei0, x0, bn0);
    k_head1    <<<128, 256, 0, stream>>>(x0, bn0, wi1, bi1, gi1, bei1, x1, bn1);
    k_final    <<<1, 256, 0, stream>>>(x1, bn1, wi2, bi2, (float*)d_out);
}

// Round 7
// 232.092 us; speedup vs baseline: 1.6342x; 1.2031x over previous
//
#include <hip/hip_runtime.h>
#include <math.h>

#define BSZ 2
#define NPOINT 128
#define NPTS 8192
#define CH_F 128
#define HEAD_BINS 12
#define KCOR 64
#define MTOT (NPOINT*KCOR)   /* 8192 corners per batch */
#define NCH 16
#define CHUNK (NPTS/NCH)     /* 512 */
#define FEAT_C 131
#define MLP2_C 256

/* ---- workspace byte offsets (256-aligned), total ~16.1 MB ---- */
#define OFF_CORNERS 0u          /* 196608 */
#define OFF_REL     196608u     /* 196608 */
#define OFF_PD      393216u     /* 2*8192*16*3 f32 = 3145728 */
#define OFF_PIX     3538944u    /* 3145728 */
#define OFF_FEATT   6684672u    /* [2][8192][128] = 8388608 */
#define OFF_W1T     15073280u   /* 67072 */
#define OFF_W2T     15140352u   /* 131072 */
#define OFF_XYZP    15271424u   /* [2][8192] float4 = 262144 */
#define OFF_H2      15533568u   /* [2][128][256] = 262144 */
#define OFF_X0      15795712u   /* [2][128][128] = 131072 */
#define OFF_X1      15926784u   /* 131072 */
#define OFF_BN0     16057856u   /* 1024 */
#define OFF_BN1     16058880u   /* 1024 */

/* ========== k_prep: decode (0..63) | w-transpose (64..79) | xyz-pack (80..143) | f-transpose (144..1167) ========== */
__global__ __launch_bounds__(256) void k_prep(const float* __restrict__ cand, const float* __restrict__ offs,
                        const float* __restrict__ angc, const float* __restrict__ angr,
                        const float* __restrict__ w1, const float* __restrict__ w2,
                        const float* __restrict__ of, const float* __restrict__ xyz,
                        float* __restrict__ corners, float* __restrict__ rel,
                        float* __restrict__ w1t, float* __restrict__ w2t,
                        float* __restrict__ ft, float4* __restrict__ xyzp)
{
    __shared__ float tile[128][17];
    __shared__ float sr[4*KCOR*3];
    __shared__ float sc_[4*KCOR*3];
    int bid = blockIdx.x;
    int t = threadIdx.x;
    if (bid < 64) {
        /* ---- decode: 4 boxes per block, one corner per thread ---- */
        int b = bid >> 5, p0 = (bid & 31) * 4;
        int lb = t >> 6, k = t & 63;
        int bp = b*NPOINT + p0 + lb;
        const float* ac = angc + bp*HEAD_BINS;
        int best = 0; float bv = ac[0];
        #pragma unroll
        for (int j = 1; j < HEAD_BINS; ++j) { float v = ac[j]; if (v > bv) { bv = v; best = j; } }
        float ares = angr[bp*HEAD_BINS + best];
        float angle = (float)best * 0.52359877559829882f + ares;
        float heading = (angle > 3.14159265358979323f) ? (angle - 6.28318530717958647f) : angle;
        float cx = cand[bp*3+0] + offs[bp*6+0];
        float cy = cand[bp*3+1] + offs[bp*6+1];
        float cz = cand[bp*3+2] + offs[bp*6+2];
        float dl = fmaxf(offs[bp*6+3]*2.0f, 0.1f);
        float dw = fmaxf(offs[bp*6+4]*2.0f, 0.1f);
        float dh = fmaxf(offs[bp*6+5]*2.0f, 0.1f);
        float chd = cosf(heading), shd = sinf(heading);
        int ix = (k>>4)&3, iy = (k>>2)&3, iz = k&3;
        float gx = (ix==3) ? 1.0f : (-1.0f + (2.0f/3.0f)*(float)ix);
        float gy = (iy==3) ? 1.0f : (-1.0f + (2.0f/3.0f)*(float)iy);
        float gz = (iz==3) ? 1.0f : (-1.0f + (2.0f/3.0f)*(float)iz);
        float wx = gx*dl, wy = gy*dw, wz = gz*dh;
        float rx = wx*chd - wy*shd;
        float ry = wx*shd + wy*chd;
        int si = (lb*KCOR + k)*3;
        sr[si+0] = rx;      sr[si+1] = ry;      sr[si+2] = wz;
        sc_[si+0] = rx+cx;  sc_[si+1] = ry+cy;  sc_[si+2] = wz+cz;
        __syncthreads();
        size_t base = ((size_t)b*MTOT + (size_t)p0*KCOR)*3;
        if (t < 192) {
            ((float4*)(rel + base))[t]     = ((const float4*)sr)[t];
            ((float4*)(corners + base))[t] = ((const float4*)sc_)[t];
        }
    } else if (bid < 80) {
        int i0 = (bid-64)*256 + t;
        for (int i = i0; i < FEAT_C*128; i += 16*256) { int o = i & 127, c = i >> 7; w1t[i] = w1[o*FEAT_C + c]; }
        for (int i = i0; i < 128*256;    i += 16*256) { int o = i & 255, c = i >> 8; w2t[i] = w2[o*128 + c]; }
    } else if (bid < 144) {
        /* ---- xyz pack: (x,y,z,|p|^2), |p|^2 with same rounding as old staging ---- */
        int i = (bid-80)*256 + t;          /* 0..16383 */
        const float* s = xyz + (size_t)i*3;
        float x = s[0], y = s[1], z = s[2];
        xyzp[i] = make_float4(x, y, z, (x*x + y*y) + z*z);
    } else {
        /* ---- feature transpose: [C][N]->[N][C], float4 both sides ---- */
        int bi = bid - 144;                /* 0..1023 */
        int b = bi >> 9;
        int n0 = (bi & 511) * 16;
        #pragma unroll
        for (int it = 0; it < 2; ++it) {
            int id = it*256 + t;
            int c = id >> 2, q = id & 3;
            float4 v = *(const float4*)(of + ((size_t)(b*CH_F + c))*NPTS + n0 + q*4);
            tile[c][q*4+0] = v.x; tile[c][q*4+1] = v.y; tile[c][q*4+2] = v.z; tile[c][q*4+3] = v.w;
        }
        __syncthreads();
        #pragma unroll
        for (int it = 0; it < 2; ++it) {
            int id = it*256 + t;
            int n = id >> 5, cq = id & 31;
            float4 o;
            o.x = tile[cq*4+0][n]; o.y = tile[cq*4+1][n]; o.z = tile[cq*4+2][n]; o.w = tile[cq*4+3][n];
            *(float4*)(ft + ((size_t)b*NPTS + n0 + n)*CH_F + cq*4) = o;
        }
    }
}

/* ========== three_nn partial: per-chunk top-3, 1 corner/thread, 1024 blocks ========== */
__global__ __launch_bounds__(256) void k_three_nn(const float4* __restrict__ xyzp,
        const float* __restrict__ corners, float* __restrict__ pd, int* __restrict__ pix)
{
    __shared__ float4 pts[CHUNK];
    int mb = blockIdx.x;   /* 0..31 : 256 corners each */
    int ch = blockIdx.y;   /* 0..15 */
    int b  = blockIdx.z;   /* 0..1  */
    int t = threadIdx.x;

    if (t < 128) {
        const float4* s4 = xyzp + ((size_t)b*NPTS + (size_t)ch*CHUNK);
        #pragma unroll
        for (int j = 0; j < 4; ++j) pts[t*4+j] = s4[t*4+j];
    }
    __syncthreads();

    int m = mb*256 + t;
    const float* cp = corners + ((size_t)b*MTOT + m)*3;
    float cx = cp[0], cy = cp[1], cz = cp[2];
    float sc = (cx*cx + cy*cy) + cz*cz;
    float s0 = 3.4e38f, s1 = 3.4e38f, s2 = 3.4e38f;
    int i0 = 0, i1 = 0, i2 = 0;
    #pragma unroll 8
    for (int n = 0; n < CHUNK; ++n) {
        float4 P = pts[n];
        float dot = fmaf(cz, P.z, fmaf(cy, P.y, cx*P.x));
        float d2 = (sc + P.w) - 2.0f*dot;        /* identical rounding to r6 */
        bool l0 = d2 < s0, l1 = d2 < s1, l2 = d2 < s2;
        i2 = l1 ? i1 : (l2 ? n : i2);
        i1 = l0 ? i0 : (l1 ? n : i1);
        i0 = l0 ? n : i0;
        s2 = __builtin_amdgcn_fmed3f(d2, s1, s2);
        s1 = __builtin_amdgcn_fmed3f(d2, s0, s1);
        s0 = fminf(d2, s0);
    }
    int nb = ch*CHUNK;
    size_t ob = (((size_t)b*MTOT + m)*NCH + ch)*3;
    pd[ob+0] = s0; pd[ob+1] = s1; pd[ob+2] = s2;
    pix[ob+0] = nb+i0; pix[ob+1] = nb+i1; pix[ob+2] = nb+i2;
}

/* ========== fused: merge top-3 + interp-gather + MLP1 -> MLP2 -> maxpool per (b,p) ========== */
__global__ __launch_bounds__(512) void k_mlp(const float* __restrict__ xyz, const float* __restrict__ corners,
        const float* __restrict__ pd, const int* __restrict__ pix,
        const float* __restrict__ featT, const float* __restrict__ rel,
        const float* __restrict__ w1t, const float* __restrict__ b1,
        const float* __restrict__ w2t, const float* __restrict__ b2,
        float* __restrict__ h2)
{
    __shared__ float lds[FEAT_C*64];          /* [c][m], 33.5 KB */
    __shared__ float swt[3][64];
    __shared__ int   sidx[3][64];
    int blk = blockIdx.x; int b = blk >> 7, p = blk & 127;
    int t = threadIdx.x;
    int g0 = b*MTOT + p*KCOR;

    if (t < 64) {
        /* merge 48 partials for corner m=t (exact tie semantics) */
        int g = g0 + t;
        float s0=3.4e38f, s1=3.4e38f, s2=3.4e38f;
        int i0=0x7fffffff, i1=0x7fffffff, i2=0x7fffffff;
        size_t base = (size_t)g*(NCH*3);
        for (int k = 0; k < NCH*3; ++k) {
            float d = pd[base+k]; int id = pix[base+k];
            bool lt0 = (d < s0) || (d == s0 && id < i0);
            bool lt1 = (d < s1) || (d == s1 && id < i1);
            bool lt2 = (d < s2) || (d == s2 && id < i2);
            s2 = lt1 ? s1 : (lt2 ? d  : s2); i2 = lt1 ? i1 : (lt2 ? id : i2);
            s1 = lt0 ? s0 : (lt1 ? d  : s1); i1 = lt0 ? i0 : (lt1 ? id : i1);
            s0 = lt0 ? d  : s0;              i0 = lt0 ? id : i0;
        }
        float cx = corners[(size_t)g*3+0], cy = corners[(size_t)g*3+1], cz = corners[(size_t)g*3+2];
        int ii[3] = {i0, i1, i2};
        float w[3];
        #pragma unroll
        for (int j = 0; j < 3; ++j) {
            const float* pp = xyz + ((size_t)b*NPTS + ii[j])*3;
            float dx = pp[0]-cx, dy = pp[1]-cy, dz = pp[2]-cz;
            float dist = sqrtf((dx*dx + dy*dy) + dz*dz);
            w[j] = 1.0f/(dist + 1e-8f);
        }
        float wsum = (w[0]+w[1])+w[2];
        #pragma unroll
        for (int j = 0; j < 3; ++j) { sidx[j][t] = ii[j]; swt[j][t] = w[j]/wsum; }
    } else if (t < 256) {
        int u = t - 64;                        /* 0..191: rel rows 0..2 */
        lds[(u % 3)*64 + (u / 3)] = rel[(size_t)g0*3 + u];
    }
    __syncthreads();

    /* gather + interp directly into lds rows 3..130 */
    const float4* fb = (const float4*)(featT + (size_t)b*NPTS*CH_F);
    #pragma unroll
    for (int it = 0; it < 4; ++it) {
        int idx = it*512 + t;                  /* 0..2047 */
        int cq = idx >> 6, m = idx & 63;
        int j0 = sidx[0][m], j1 = sidx[1][m], j2 = sidx[2][m];
        float w0 = swt[0][m], w1 = swt[1][m], w2 = swt[2][m];
        float4 f0 = fb[(size_t)j0*32 + cq];
        float4 f1 = fb[(size_t)j1*32 + cq];
        float4 f2 = fb[(size_t)j2*32 + cq];
        float4 v;
        v.x = (f0.x*w0 + f1.x*w1) + f2.x*w2;
        v.y = (f0.y*w0 + f1.y*w1) + f2.y*w2;
        v.z = (f0.z*w0 + f1.z*w1) + f2.z*w2;
        v.w = (f0.w*w0 + f1.w*w1) + f2.w*w2;
        int c0 = 3 + cq*4;
        lds[(c0+0)*64+m] = v.x; lds[(c0+1)*64+m] = v.y;
        lds[(c0+2)*64+m] = v.z; lds[(c0+3)*64+m] = v.w;
    }
    __syncthreads();

    /* phase1: o = og*4+i (32 og), m = mg*4+j (16 mg) */
    int og = t >> 4, mg = t & 15;
    float acc[4][4];
    #pragma unroll
    for (int i = 0; i < 4; ++i) { float bb = b1[og*4+i];
        #pragma unroll
        for (int j = 0; j < 4; ++j) acc[i][j] = bb; }
    #pragma unroll 4
    for (int c = 0; c < FEAT_C; ++c) {
        float4 wv = *(const float4*)(w1t + c*128 + og*4);
        float4 f0 = *(const float4*)(&lds[c*64 + mg*4]);
        float fv[4] = {f0.x,f0.y,f0.z,f0.w};
        float wa[4] = {wv.x,wv.y,wv.z,wv.w};
        #pragma unroll
        for (int i = 0; i < 4; ++i)
            #pragma unroll
            for (int j = 0; j < 4; ++j)
                acc[i][j] = fmaf(wa[i], fv[j], acc[i][j]);
    }
    __syncthreads();
    #pragma unroll
    for (int i = 0; i < 4; ++i) {
        float4 r0 = make_float4(fmaxf(acc[i][0],0.f), fmaxf(acc[i][1],0.f), fmaxf(acc[i][2],0.f), fmaxf(acc[i][3],0.f));
        *(float4*)(&lds[(og*4+i)*64 + mg*4]) = r0;
    }
    __syncthreads();

    /* phase2: o = og2*4+i (64 og2), m = mg2*8+j (8 mg2) */
    int og2 = t >> 3, mg2 = t & 7;
    float a2[4][8];
    #pragma unroll
    for (int i = 0; i < 4; ++i) { float bb = b2[og2*4+i];
        #pragma unroll
        for (int j = 0; j < 8; ++j) a2[i][j] = bb; }
    #pragma unroll 2
    for (int c = 0; c < 128; ++c) {
        float4 wv = *(const float4*)(w2t + c*MLP2_C + og2*4);
        float4 f0 = *(const float4*)(&lds[c*64 + mg2*8]);
        float4 f1 = *(const float4*)(&lds[c*64 + mg2*8 + 4]);
        float fv[8] = {f0.x,f0.y,f0.z,f0.w,f1.x,f1.y,f1.z,f1.w};
        float wa[4] = {wv.x,wv.y,wv.z,wv.w};
        #pragma unroll
        for (int i = 0; i < 4; ++i)
            #pragma unroll
            for (int j = 0; j < 8; ++j)
                a2[i][j] = fmaf(wa[i], fv[j], a2[i][j]);
    }
    float mx[4];
    #pragma unroll
    for (int i = 0; i < 4; ++i) {
        float m0 = a2[i][0];
        #pragma unroll
        for (int j = 1; j < 8; ++j) m0 = fmaxf(m0, a2[i][j]);
        mx[i] = fmaxf(m0, 0.0f);
    }
    #pragma unroll
    for (int off = 1; off < 8; off <<= 1)
        #pragma unroll
        for (int i = 0; i < 4; ++i)
            mx[i] = fmaxf(mx[i], __shfl_xor(mx[i], off, 64));
    if (mg2 == 0)   /* h2 layout: [b][p][o], float4 store */
        *(float4*)(&h2[((size_t)b*NPOINT + p)*MLP2_C + og2*4]) = make_float4(mx[0],mx[1],mx[2],mx[3]);
}

/* ========== IoU head: gemm + BN stats fused; x layouts are [b][p][c] ========== */
__global__ __launch_bounds__(256) void k_head0(const float* __restrict__ h2, const float* __restrict__ w0,
                        const float* __restrict__ b0, const float* __restrict__ g0,
                        const float* __restrict__ be0,
                        float* __restrict__ x0, float* __restrict__ bn0)
{
    __shared__ float ssum[256], ssq[256];
    int o = blockIdx.x;            /* 0..127 */
    int t = threadIdx.x;           /* 256 = (b,p) */
    int b = t >> 7, p = t & 127;
    const float4* hb = (const float4*)(h2 + ((size_t)b*NPOINT + p)*MLP2_C);
    const float4* wr = (const float4*)(w0 + (size_t)o*MLP2_C);
    float acc = b0[o];
    #pragma unroll 8
    for (int cq = 0; cq < 64; ++cq) {
        float4 h = hb[cq], w = wr[cq];
        acc = fmaf(h.x, w.x, acc); acc = fmaf(h.y, w.y, acc);
        acc = fmaf(h.z, w.z, acc); acc = fmaf(h.w, w.w, acc);
    }
    x0[((size_t)b*NPOINT + p)*128 + o] = acc;
    ssum[t] = acc; ssq[t] = acc*acc;
    __syncthreads();
    if (t < 128) { ssum[t] += ssum[t+128]; ssq[t] += ssq[t+128]; }
    __syncthreads();
    if (t < 64) {
        float s = ssum[t] + ssum[t+64];
        float q = ssq[t] + ssq[t+64];
        #pragma unroll
        for (int off = 32; off >= 1; off >>= 1) {
            s += __shfl_down(s, off, 64);
            q += __shfl_down(q, off, 64);
        }
        if (t == 0) {
            float mean = s * (1.0f/256.0f);
            float var  = q * (1.0f/256.0f) - mean*mean;
            if (var < 0.f) var = 0.f;
            float scale = g0[o] / sqrtf(var + 1e-5f);
            bn0[o]       = scale;
            bn0[128 + o] = be0[o] - mean*scale;
        }
    }
}

__global__ __launch_bounds__(256) void k_head1(const float* __restrict__ x0, const float* __restrict__ bn0,
                        const float* __restrict__ w1, const float* __restrict__ b1,
                        const float* __restrict__ g1, const float* __restrict__ be1,
                        float* __restrict__ x1, float* __restrict__ bn1)
{
    __shared__ float ssum[256], ssq[256];
    int o = blockIdx.x;
    int t = threadIdx.x;
    int b = t >> 7, p = t & 127;
    const float4* xb = (const float4*)(x0 + ((size_t)b*NPOINT + p)*128);
    const float4* wr = (const float4*)(w1 + (size_t)o*128);
    float acc = b1[o];
    #pragma unroll 8
    for (int cq = 0; cq < 32; ++cq) {
        float4 xv = xb[cq], wv = wr[cq];
        float4 sc = *(const float4*)(bn0 + cq*4);
        float4 sh = *(const float4*)(bn0 + 128 + cq*4);
        acc = fmaf(wv.x, fmaxf(fmaf(xv.x, sc.x, sh.x), 0.0f), acc);
        acc = fmaf(wv.y, fmaxf(fmaf(xv.y, sc.y, sh.y), 0.0f), acc);
        acc = fmaf(wv.z, fmaxf(fmaf(xv.z, sc.z, sh.z), 0.0f), acc);
        acc = fmaf(wv.w, fmaxf(fmaf(xv.w, sc.w, sh.w), 0.0f), acc);
    }
    x1[((size_t)b*NPOINT + p)*128 + o] = acc;
    ssum[t] = acc; ssq[t] = acc*acc;
    __syncthreads();
    if (t < 128) { ssum[t] += ssum[t+128]; ssq[t] += ssq[t+128]; }
    __syncthreads();
    if (t < 64) {
        float s = ssum[t] + ssum[t+64];
        float q = ssq[t] + ssq[t+64];
        #pragma unroll
        for (int off = 32; off >= 1; off >>= 1) {
            s += __shfl_down(s, off, 64);
            q += __shfl_down(q, off, 64);
        }
        if (t == 0) {
            float mean = s * (1.0f/256.0f);
            float var  = q * (1.0f/256.0f) - mean*mean;
            if (var < 0.f) var = 0.f;
            float scale = g1[o] / sqrtf(var + 1e-5f);
            bn1[o]       = scale;
            bn1[128 + o] = be1[o] - mean*scale;
        }
    }
}

__global__ void k_final(const float* __restrict__ x1, const float* __restrict__ bn1,
                        const float* __restrict__ w2, const float* __restrict__ b2,
                        float* __restrict__ out)
{
    int t = threadIdx.x;  /* 256 */
    int b = t >> 7, p = t & 127;
    const float4* xb = (const float4*)(x1 + ((size_t)b*NPOINT + p)*128);
    float acc = b2[0];
    #pragma unroll 8
    for (int cq = 0; cq < 32; ++cq) {
        float4 xv = xb[cq];
        float4 wv = *(const float4*)(w2 + cq*4);
        float4 sc = *(const float4*)(bn1 + cq*4);
        float4 sh = *(const float4*)(bn1 + 128 + cq*4);
        acc = fmaf(wv.x, fmaxf(fmaf(xv.x, sc.x, sh.x), 0.0f), acc);
        acc = fmaf(wv.y, fmaxf(fmaf(xv.y, sc.y, sh.y), 0.0f), acc);
        acc = fmaf(wv.z, fmaxf(fmaf(xv.z, sc.z, sh.z), 0.0f), acc);
        acc = fmaf(wv.w, fmaxf(fmaf(xv.w, sc.w, sh.w), 0.0f), acc);
    }
    out[b*NPOINT + p] = acc;
}

extern "C" void kernel_launch(void* const* d_in, const int* in_sizes, int n_in,
                              void* d_out, int out_size, void* d_ws, size_t ws_size,
                              hipStream_t stream)
{
    const float* xyz   = (const float*)d_in[0];
    const float* ofeat = (const float*)d_in[1];
    const float* cand  = (const float*)d_in[2];
    /* d_in[3] = pred_cls, unused */
    const float* offs  = (const float*)d_in[4];
    const float* angc  = (const float*)d_in[5];
    const float* angr  = (const float*)d_in[6];
    const float* w1    = (const float*)d_in[7];
    const float* b1    = (const float*)d_in[8];
    const float* w2    = (const float*)d_in[9];
    const float* b2    = (const float*)d_in[10];
    const float* wi0   = (const float*)d_in[11];
    const float* bi0   = (const float*)d_in[12];
    const float* gi0   = (const float*)d_in[13];
    const float* bei0  = (const float*)d_in[14];
    const float* wi1   = (const float*)d_in[15];
    const float* bi1   = (const float*)d_in[16];
    const float* gi1   = (const float*)d_in[17];
    const float* bei1  = (const float*)d_in[18];
    const float* wi2   = (const float*)d_in[19];
    const float* bi2   = (const float*)d_in[20];

    char* ws = (char*)d_ws;
    float*  corners = (float*)(ws + OFF_CORNERS);
    float*  rel     = (float*)(ws + OFF_REL);
    float*  pd      = (float*)(ws + OFF_PD);
    int*    pix     = (int*)  (ws + OFF_PIX);
    float*  featT   = (float*)(ws + OFF_FEATT);
    float*  w1t     = (float*)(ws + OFF_W1T);
    float*  w2t     = (float*)(ws + OFF_W2T);
    float4* xyzp    = (float4*)(ws + OFF_XYZP);
    float*  h2      = (float*)(ws + OFF_H2);
    float*  x0      = (float*)(ws + OFF_X0);
    float*  x1      = (float*)(ws + OFF_X1);
    float*  bn0     = (float*)(ws + OFF_BN0);
    float*  bn1     = (float*)(ws + OFF_BN1);

    k_prep     <<<1168, 256, 0, stream>>>(cand, offs, angc, angr, w1, w2, ofeat, xyz,
                                          corners, rel, w1t, w2t, featT, xyzp);
    k_three_nn <<<dim3(32,16,2), 256, 0, stream>>>(xyzp, corners, pd, pix);
    k_mlp      <<<256, 512, 0, stream>>>(xyz, corners, pd, pix, featT, rel,
                                         w1t, b1, w2t, b2, h2);
    k_head0    <<<128, 256, 0, stream>>>(h2, wi0, bi0, gi0, bei0, x0, bn0);
    k_head1    <<<128, 256, 0, stream>>>(x0, bn0, wi1, bi1, gi1, bei1, x1, bn1);
    k_final    <<<1, 256, 0, stream>>>(x1, bn1, wi2, bi2, (float*)d_out);
}

// Round 8
// 230.258 us; speedup vs baseline: 1.6472x; 1.0080x over previous
//
#include <hip/hip_runtime.h>
#include <math.h>

#define BSZ 2
#define NPOINT 128
#define NPTS 8192
#define CH_F 128
#define HEAD_BINS 12
#define KCOR 64
#define MTOT (NPOINT*KCOR)   /* 8192 corners per batch */
#define FEAT_C 131
#define MLP2_C 256

/* ---- workspace byte offsets (256-aligned) ---- */
#define OFF_CORNERS 0u          /* 196608 */
#define OFF_REL     196608u     /* 196608 */
#define OFF_IDX3    393216u     /* [2][8192][3] int = 196608 */
#define OFF_W3      589824u     /* [2][8192][3] f32 = 196608 */
#define OFF_FEATT   6684672u    /* [2][8192][128] = 8388608 */
#define OFF_W1T     15073280u   /* 67072 */
#define OFF_W2T     15140352u   /* 131072 */
#define OFF_XYZP    15271424u   /* [2][8192] float4 = 262144 */
#define OFF_H2      15533568u   /* [2][128][256] = 262144 */
#define OFF_X0      15795712u   /* [2][128][128] = 131072 */
#define OFF_X1      15926784u   /* 131072 */
#define OFF_BN0     16057856u   /* 1024 */
#define OFF_BN1     16058880u   /* 1024 */

/* ========== k_prep: decode (0..63) | w-transpose (64..79) | xyz-pack (80..143) | f-transpose (144..1167) ========== */
__global__ __launch_bounds__(256) void k_prep(const float* __restrict__ cand, const float* __restrict__ offs,
                        const float* __restrict__ angc, const float* __restrict__ angr,
                        const float* __restrict__ w1, const float* __restrict__ w2,
                        const float* __restrict__ of, const float* __restrict__ xyz,
                        float* __restrict__ corners, float* __restrict__ rel,
                        float* __restrict__ w1t, float* __restrict__ w2t,
                        float* __restrict__ ft, float4* __restrict__ xyzp)
{
    __shared__ float tile[128][17];
    __shared__ float sr[4*KCOR*3];
    __shared__ float sc_[4*KCOR*3];
    int bid = blockIdx.x;
    int t = threadIdx.x;
    if (bid < 64) {
        int b = bid >> 5, p0 = (bid & 31) * 4;
        int lb = t >> 6, k = t & 63;
        int bp = b*NPOINT + p0 + lb;
        const float* ac = angc + bp*HEAD_BINS;
        int best = 0; float bv = ac[0];
        #pragma unroll
        for (int j = 1; j < HEAD_BINS; ++j) { float v = ac[j]; if (v > bv) { bv = v; best = j; } }
        float ares = angr[bp*HEAD_BINS + best];
        float angle = (float)best * 0.52359877559829882f + ares;
        float heading = (angle > 3.14159265358979323f) ? (angle - 6.28318530717958647f) : angle;
        float cx = cand[bp*3+0] + offs[bp*6+0];
        float cy = cand[bp*3+1] + offs[bp*6+1];
        float cz = cand[bp*3+2] + offs[bp*6+2];
        float dl = fmaxf(offs[bp*6+3]*2.0f, 0.1f);
        float dw = fmaxf(offs[bp*6+4]*2.0f, 0.1f);
        float dh = fmaxf(offs[bp*6+5]*2.0f, 0.1f);
        float chd = cosf(heading), shd = sinf(heading);
        int ix = (k>>4)&3, iy = (k>>2)&3, iz = k&3;
        float gx = (ix==3) ? 1.0f : (-1.0f + (2.0f/3.0f)*(float)ix);
        float gy = (iy==3) ? 1.0f : (-1.0f + (2.0f/3.0f)*(float)iy);
        float gz = (iz==3) ? 1.0f : (-1.0f + (2.0f/3.0f)*(float)iz);
        float wx = gx*dl, wy = gy*dw, wz = gz*dh;
        float rx = wx*chd - wy*shd;
        float ry = wx*shd + wy*chd;
        int si = (lb*KCOR + k)*3;
        sr[si+0] = rx;      sr[si+1] = ry;      sr[si+2] = wz;
        sc_[si+0] = rx+cx;  sc_[si+1] = ry+cy;  sc_[si+2] = wz+cz;
        __syncthreads();
        size_t base = ((size_t)b*MTOT + (size_t)p0*KCOR)*3;
        if (t < 192) {
            ((float4*)(rel + base))[t]     = ((const float4*)sr)[t];
            ((float4*)(corners + base))[t] = ((const float4*)sc_)[t];
        }
    } else if (bid < 80) {
        int i0 = (bid-64)*256 + t;
        for (int i = i0; i < FEAT_C*128; i += 16*256) { int o = i & 127, c = i >> 7; w1t[i] = w1[o*FEAT_C + c]; }
        for (int i = i0; i < 128*256;    i += 16*256) { int o = i & 255, c = i >> 8; w2t[i] = w2[o*128 + c]; }
    } else if (bid < 144) {
        int i = (bid-80)*256 + t;          /* 0..16383 */
        const float* s = xyz + (size_t)i*3;
        float x = s[0], y = s[1], z = s[2];
        xyzp[i] = make_float4(x, y, z, (x*x + y*y) + z*z);
    } else {
        int bi = bid - 144;                /* 0..1023 */
        int b = bi >> 9;
        int n0 = (bi & 511) * 16;
        #pragma unroll
        for (int it = 0; it < 2; ++it) {
            int id = it*256 + t;
            int c = id >> 2, q = id & 3;
            float4 v = *(const float4*)(of + ((size_t)(b*CH_F + c))*NPTS + n0 + q*4);
            tile[c][q*4+0] = v.x; tile[c][q*4+1] = v.y; tile[c][q*4+2] = v.z; tile[c][q*4+3] = v.w;
        }
        __syncthreads();
        #pragma unroll
        for (int it = 0; it < 2; ++it) {
            int id = it*256 + t;
            int n = id >> 5, cq = id & 31;
            float4 o;
            o.x = tile[cq*4+0][n]; o.y = tile[cq*4+1][n]; o.z = tile[cq*4+2][n]; o.w = tile[cq*4+3][n];
            *(float4*)(ft + ((size_t)b*NPTS + n0 + n)*CH_F + cq*4) = o;
        }
    }
}

/* ========== three_nn: exact box-prefilter + refine, final idx/weights out ==========
   block = (b, p, half): 32 corners of one box; 512 threads.
   Bound: any point in a corner's top-3 has d(p,center) <= r3(center) + 2H,
   H = sqrt(dl^2+dw^2+dh^2) >= max corner offset (rotation preserves norm).      */
__global__ __launch_bounds__(512) void k_three_nn(const float4* __restrict__ xyzp,
        const float* __restrict__ cand, const float* __restrict__ offs,
        const float* __restrict__ corners,
        int* __restrict__ idx3, float* __restrict__ w3)
{
    __shared__ int   lidx[NPTS];        /* candidate indices (worst case all) 32 KB */
    __shared__ float red[1752];         /* top-3 reduce: 512*3 | 64*3 | 8*3 */
    __shared__ float pms[512*3];        /* refine partial dists */
    __shared__ int   pmi[512*3];        /* refine partial indices */
    __shared__ int   s_cnt;
    __shared__ float s_T;

    int bid = blockIdx.x;               /* 0..511 */
    int b    = bid >> 8;
    int p    = (bid >> 1) & 127;
    int half = bid & 1;
    int t = threadIdx.x;
    int bp = b*NPOINT + p;

    /* center + H (uniform scalar loads) */
    float cx = cand[bp*3+0] + offs[bp*6+0];
    float cy = cand[bp*3+1] + offs[bp*6+1];
    float cz = cand[bp*3+2] + offs[bp*6+2];
    float dl = fmaxf(offs[bp*6+3]*2.0f, 0.1f);
    float dw = fmaxf(offs[bp*6+4]*2.0f, 0.1f);
    float dh = fmaxf(offs[bp*6+5]*2.0f, 0.1f);
    float H  = sqrtf((dl*dl + dw*dw) + dh*dh);
    float scc = (cx*cx + cy*cy) + cz*cz;

    const float4* xb = xyzp + (size_t)b*NPTS;

    /* ---- pass 1: center distance to all points, cache d2, per-thread top-3 ---- */
    float d2c[16];
    float a0 = 3.4e38f, a1 = 3.4e38f, a2 = 3.4e38f;
    #pragma unroll
    for (int i = 0; i < 16; ++i) {
        float4 P = xb[i*512 + t];                    /* coalesced */
        float dot = fmaf(cz, P.z, fmaf(cy, P.y, cx*P.x));
        float d2 = (scc + P.w) - 2.0f*dot;
        d2c[i] = d2;
        a2 = __builtin_amdgcn_fmed3f(d2, a1, a2);
        a1 = __builtin_amdgcn_fmed3f(d2, a0, a1);
        a0 = fminf(d2, a0);
    }
    red[t*3+0] = a0; red[t*3+1] = a1; red[t*3+2] = a2;
    if (t == 0) s_cnt = 0;
    __syncthreads();
    if (t < 64) {
        float m0 = 3.4e38f, m1 = 3.4e38f, m2 = 3.4e38f;
        for (int s = t*8; s < t*8+8; ++s) {
            #pragma unroll
            for (int j = 0; j < 3; ++j) {
                float v = red[s*3+j];
                m2 = __builtin_amdgcn_fmed3f(v, m1, m2);
                m1 = __builtin_amdgcn_fmed3f(v, m0, m1);
                m0 = fminf(v, m0);
            }
        }
        red[1536 + t*3+0] = m0; red[1536 + t*3+1] = m1; red[1536 + t*3+2] = m2;
    }
    __syncthreads();
    if (t < 8) {
        float m0 = 3.4e38f, m1 = 3.4e38f, m2 = 3.4e38f;
        for (int s = t*8; s < t*8+8; ++s) {
            #pragma unroll
            for (int j = 0; j < 3; ++j) {
                float v = red[1536 + s*3+j];
                m2 = __builtin_amdgcn_fmed3f(v, m1, m2);
                m1 = __builtin_amdgcn_fmed3f(v, m0, m1);
                m0 = fminf(v, m0);
            }
        }
        red[1728 + t*3+0] = m0; red[1728 + t*3+1] = m1; red[1728 + t*3+2] = m2;
    }
    __syncthreads();
    if (t == 0) {
        float m0 = 3.4e38f, m1 = 3.4e38f, m2 = 3.4e38f;
        for (int s = 0; s < 8; ++s) {
            #pragma unroll
            for (int j = 0; j < 3; ++j) {
                float v = red[1728 + s*3+j];
                m2 = __builtin_amdgcn_fmed3f(v, m1, m2);
                m1 = __builtin_amdgcn_fmed3f(v, m0, m1);
                m0 = fminf(v, m0);
            }
        }
        float r3 = sqrtf(fmaxf(m2, 0.0f));
        float rad = r3 + 2.0f*H;
        s_T = rad*rad*1.0002f + 0.25f;   /* generous fp margin — exactness-safe */
    }
    __syncthreads();

    /* ---- pass 2: compact candidate indices ---- */
    float T = s_T;
    #pragma unroll
    for (int i = 0; i < 16; ++i) {
        if (d2c[i] <= T) {
            int pos = atomicAdd(&s_cnt, 1);
            lidx[pos] = i*512 + t;
        }
    }
    __syncthreads();
    int C = s_cnt;

    /* ---- refine: 32 corners x C candidates, 16 threads/corner ---- */
    int ck  = half*32 + (t >> 4);        /* corner 0..63 within box */
    int sub = t & 15;
    size_t crow = (size_t)b*MTOT + p*KCOR + ck;
    float ox = corners[crow*3+0], oy = corners[crow*3+1], oz = corners[crow*3+2];
    float so = (ox*ox + oy*oy) + oz*oz;
    float s0 = 3.4e38f, s1 = 3.4e38f, s2 = 3.4e38f;
    int i0 = 0x7fffffff, i1 = 0x7fffffff, i2 = 0x7fffffff;
    for (int j = sub; j < C; j += 16) {
        int idx = lidx[j];
        float4 P = xb[idx];
        float dot = fmaf(oz, P.z, fmaf(oy, P.y, ox*P.x));
        float d2 = (so + P.w) - 2.0f*dot;            /* bit-identical to r7 formula */
        bool lt0 = (d2 < s0) || (d2 == s0 && idx < i0);
        bool lt1 = (d2 < s1) || (d2 == s1 && idx < i1);
        bool lt2 = (d2 < s2) || (d2 == s2 && idx < i2);
        s2 = lt1 ? s1 : (lt2 ? d2  : s2); i2 = lt1 ? i1 : (lt2 ? idx : i2);
        s1 = lt0 ? s0 : (lt1 ? d2  : s1); i1 = lt0 ? i0 : (lt1 ? idx : i1);
        s0 = lt0 ? d2 : s0;               i0 = lt0 ? idx : i0;
    }
    pms[t*3+0] = s0; pms[t*3+1] = s1; pms[t*3+2] = s2;
    pmi[t*3+0] = i0; pmi[t*3+1] = i1; pmi[t*3+2] = i2;
    __syncthreads();

    /* ---- final merge (one lane per corner) + weights + store ---- */
    if (t < 32) {
        float f0 = 3.4e38f, f1 = 3.4e38f, f2 = 3.4e38f;
        int   j0 = 0x7fffffff, j1 = 0x7fffffff, j2 = 0x7fffffff;
        for (int tt = t*16; tt < t*16+16; ++tt) {
            #pragma unroll
            for (int j = 0; j < 3; ++j) {
                float d = pms[tt*3+j]; int id = pmi[tt*3+j];
                bool lt0 = (d < f0) || (d == f0 && id < j0);
                bool lt1 = (d < f1) || (d == f1 && id < j1);
                bool lt2 = (d < f2) || (d == f2 && id < j2);
                f2 = lt1 ? f1 : (lt2 ? d  : f2); j2 = lt1 ? j1 : (lt2 ? id : j2);
                f1 = lt0 ? f0 : (lt1 ? d  : f1); j1 = lt0 ? j0 : (lt1 ? id : j1);
                f0 = lt0 ? d  : f0;              j0 = lt0 ? id : j0;
            }
        }
        int ckf = half*32 + t;
        size_t row = (size_t)b*MTOT + p*KCOR + ckf;
        float qx = corners[row*3+0], qy = corners[row*3+1], qz = corners[row*3+2];
        int ii[3] = {j0, j1, j2};
        float w[3];
        #pragma unroll
        for (int j = 0; j < 3; ++j) {
            float4 P = xb[ii[j]];
            float dx = P.x - qx, dy = P.y - qy, dz = P.z - qz;
            float dist = sqrtf((dx*dx + dy*dy) + dz*dz);
            w[j] = 1.0f/(dist + 1e-8f);
        }
        float wsum = (w[0]+w[1])+w[2];
        #pragma unroll
        for (int j = 0; j < 3; ++j) {
            idx3[row*3+j] = ii[j];
            w3[row*3+j]   = w[j]/wsum;
        }
    }
}

/* ========== fused: gather-interp + MLP1 -> MLP2 -> maxpool per (b,p) ========== */
__global__ __launch_bounds__(512) void k_mlp(const int* __restrict__ idx3, const float* __restrict__ w3,
        const float* __restrict__ featT, const float* __restrict__ rel,
        const float* __restrict__ w1t, const float* __restrict__ b1,
        const float* __restrict__ w2t, const float* __restrict__ b2,
        float* __restrict__ h2)
{
    __shared__ float lds[FEAT_C*64];          /* [c][m], 33.5 KB */
    __shared__ float swt[3][64];
    __shared__ int   sidx[3][64];
    int blk = blockIdx.x; int b = blk >> 7, p = blk & 127;
    int t = threadIdx.x;
    int g0 = b*MTOT + p*KCOR;

    if (t < 64) {
        size_t row = (size_t)(g0 + t)*3;
        #pragma unroll
        for (int j = 0; j < 3; ++j) { sidx[j][t] = idx3[row+j]; swt[j][t] = w3[row+j]; }
    } else if (t < 256) {
        int u = t - 64;                        /* 0..191: rel rows 0..2 */
        lds[(u % 3)*64 + (u / 3)] = rel[(size_t)g0*3 + u];
    }
    __syncthreads();

    const float4* fb = (const float4*)(featT + (size_t)b*NPTS*CH_F);
    #pragma unroll
    for (int it = 0; it < 4; ++it) {
        int idx = it*512 + t;                  /* 0..2047 */
        int cq = idx >> 6, m = idx & 63;
        int j0 = sidx[0][m], j1 = sidx[1][m], j2 = sidx[2][m];
        float w0 = swt[0][m], w1 = swt[1][m], w2 = swt[2][m];
        float4 f0 = fb[(size_t)j0*32 + cq];
        float4 f1 = fb[(size_t)j1*32 + cq];
        float4 f2 = fb[(size_t)j2*32 + cq];
        float4 v;
        v.x = (f0.x*w0 + f1.x*w1) + f2.x*w2;
        v.y = (f0.y*w0 + f1.y*w1) + f2.y*w2;
        v.z = (f0.z*w0 + f1.z*w1) + f2.z*w2;
        v.w = (f0.w*w0 + f1.w*w1) + f2.w*w2;
        int c0 = 3 + cq*4;
        lds[(c0+0)*64+m] = v.x; lds[(c0+1)*64+m] = v.y;
        lds[(c0+2)*64+m] = v.z; lds[(c0+3)*64+m] = v.w;
    }
    __syncthreads();

    /* phase1: o = og*4+i (32 og), m = mg*4+j (16 mg) */
    int og = t >> 4, mg = t & 15;
    float acc[4][4];
    #pragma unroll
    for (int i = 0; i < 4; ++i) { float bb = b1[og*4+i];
        #pragma unroll
        for (int j = 0; j < 4; ++j) acc[i][j] = bb; }
    #pragma unroll 4
    for (int c = 0; c < FEAT_C; ++c) {
        float4 wv = *(const float4*)(w1t + c*128 + og*4);
        float4 f0 = *(const float4*)(&lds[c*64 + mg*4]);
        float fv[4] = {f0.x,f0.y,f0.z,f0.w};
        float wa[4] = {wv.x,wv.y,wv.z,wv.w};
        #pragma unroll
        for (int i = 0; i < 4; ++i)
            #pragma unroll
            for (int j = 0; j < 4; ++j)
                acc[i][j] = fmaf(wa[i], fv[j], acc[i][j]);
    }
    __syncthreads();
    #pragma unroll
    for (int i = 0; i < 4; ++i) {
        float4 r0 = make_float4(fmaxf(acc[i][0],0.f), fmaxf(acc[i][1],0.f), fmaxf(acc[i][2],0.f), fmaxf(acc[i][3],0.f));
        *(float4*)(&lds[(og*4+i)*64 + mg*4]) = r0;
    }
    __syncthreads();

    /* phase2: o = og2*4+i (64 og2), m = mg2*8+j (8 mg2) */
    int og2 = t >> 3, mg2 = t & 7;
    float a2[4][8];
    #pragma unroll
    for (int i = 0; i < 4; ++i) { float bb = b2[og2*4+i];
        #pragma unroll
        for (int j = 0; j < 8; ++j) a2[i][j] = bb; }
    #pragma unroll 2
    for (int c = 0; c < 128; ++c) {
        float4 wv = *(const float4*)(w2t + c*MLP2_C + og2*4);
        float4 f0 = *(const float4*)(&lds[c*64 + mg2*8]);
        float4 f1 = *(const float4*)(&lds[c*64 + mg2*8 + 4]);
        float fv[8] = {f0.x,f0.y,f0.z,f0.w,f1.x,f1.y,f1.z,f1.w};
        float wa[4] = {wv.x,wv.y,wv.z,wv.w};
        #pragma unroll
        for (int i = 0; i < 4; ++i)
            #pragma unroll
            for (int j = 0; j < 8; ++j)
                a2[i][j] = fmaf(wa[i], fv[j], a2[i][j]);
    }
    float mx[4];
    #pragma unroll
    for (int i = 0; i < 4; ++i) {
        float m0 = a2[i][0];
        #pragma unroll
        for (int j = 1; j < 8; ++j) m0 = fmaxf(m0, a2[i][j]);
        mx[i] = fmaxf(m0, 0.0f);
    }
    #pragma unroll
    for (int off = 1; off < 8; off <<= 1)
        #pragma unroll
        for (int i = 0; i < 4; ++i)
            mx[i] = fmaxf(mx[i], __shfl_xor(mx[i], off, 64));
    if (mg2 == 0)   /* h2 layout: [b][p][o] */
        *(float4*)(&h2[((size_t)b*NPOINT + p)*MLP2_C + og2*4]) = make_float4(mx[0],mx[1],mx[2],mx[3]);
}

/* ========== IoU head: gemm + BN stats fused; x layouts are [b][p][c] ========== */
__global__ __launch_bounds__(256) void k_head0(const float* __restrict__ h2, const float* __restrict__ w0,
                        const float* __restrict__ b0, const float* __restrict__ g0,
                        const float* __restrict__ be0,
                        float* __restrict__ x0, float* __restrict__ bn0)
{
    __shared__ float ssum[256], ssq[256];
    int o = blockIdx.x;            /* 0..127 */
    int t = threadIdx.x;           /* 256 = (b,p) */
    int b = t >> 7, p = t & 127;
    const float4* hb = (const float4*)(h2 + ((size_t)b*NPOINT + p)*MLP2_C);
    const float4* wr = (const float4*)(w0 + (size_t)o*MLP2_C);
    float acc = b0[o];
    #pragma unroll 8
    for (int cq = 0; cq < 64; ++cq) {
        float4 h = hb[cq], w = wr[cq];
        acc = fmaf(h.x, w.x, acc); acc = fmaf(h.y, w.y, acc);
        acc = fmaf(h.z, w.z, acc); acc = fmaf(h.w, w.w, acc);
    }
    x0[((size_t)b*NPOINT + p)*128 + o] = acc;
    ssum[t] = acc; ssq[t] = acc*acc;
    __syncthreads();
    if (t < 128) { ssum[t] += ssum[t+128]; ssq[t] += ssq[t+128]; }
    __syncthreads();
    if (t < 64) {
        float s = ssum[t] + ssum[t+64];
        float q = ssq[t] + ssq[t+64];
        #pragma unroll
        for (int off = 32; off >= 1; off >>= 1) {
            s += __shfl_down(s, off, 64);
            q += __shfl_down(q, off, 64);
        }
        if (t == 0) {
            float mean = s * (1.0f/256.0f);
            float var  = q * (1.0f/256.0f) - mean*mean;
            if (var < 0.f) var = 0.f;
            float scale = g0[o] / sqrtf(var + 1e-5f);
            bn0[o]       = scale;
            bn0[128 + o] = be0[o] - mean*scale;
        }
    }
}

__global__ __launch_bounds__(256) void k_head1(const float* __restrict__ x0, const float* __restrict__ bn0,
                        const float* __restrict__ w1, const float* __restrict__ b1,
                        const float* __restrict__ g1, const float* __restrict__ be1,
                        float* __restrict__ x1, float* __restrict__ bn1)
{
    __shared__ float ssum[256], ssq[256];
    int o = blockIdx.x;
    int t = threadIdx.x;
    int b = t >> 7, p = t & 127;
    const float4* xb = (const float4*)(x0 + ((size_t)b*NPOINT + p)*128);
    const float4* wr = (const float4*)(w1 + (size_t)o*128);
    float acc = b1[o];
    #pragma unroll 8
    for (int cq = 0; cq < 32; ++cq) {
        float4 xv = xb[cq], wv = wr[cq];
        float4 sc = *(const float4*)(bn0 + cq*4);
        float4 sh = *(const float4*)(bn0 + 128 + cq*4);
        acc = fmaf(wv.x, fmaxf(fmaf(xv.x, sc.x, sh.x), 0.0f), acc);
        acc = fmaf(wv.y, fmaxf(fmaf(xv.y, sc.y, sh.y), 0.0f), acc);
        acc = fmaf(wv.z, fmaxf(fmaf(xv.z, sc.z, sh.z), 0.0f), acc);
        acc = fmaf(wv.w, fmaxf(fmaf(xv.w, sc.w, sh.w), 0.0f), acc);
    }
    x1[((size_t)b*NPOINT + p)*128 + o] = acc;
    ssum[t] = acc; ssq[t] = acc*acc;
    __syncthreads();
    if (t < 128) { ssum[t] += ssum[t+128]; ssq[t] += ssq[t+128]; }
    __syncthreads();
    if (t < 64) {
        float s = ssum[t] + ssum[t+64];
        float q = ssq[t] + ssq[t+64];
        #pragma unroll
        for (int off = 32; off >= 1; off >>= 1) {
            s += __shfl_down(s, off, 64);
            q += __shfl_down(q, off, 64);
        }
        if (t == 0) {
            float mean = s * (1.0f/256.0f);
            float var  = q * (1.0f/256.0f) - mean*mean;
            if (var < 0.f) var = 0.f;
            float scale = g1[o] / sqrtf(var + 1e-5f);
            bn1[o]       = scale;
            bn1[128 + o] = be1[o] - mean*scale;
        }
    }
}

__global__ void k_final(const float* __restrict__ x1, const float* __restrict__ bn1,
                        const float* __restrict__ w2, const float* __restrict__ b2,
                        float* __restrict__ out)
{
    int t = threadIdx.x;  /* 256 */
    int b = t >> 7, p = t & 127;
    const float4* xb = (const float4*)(x1 + ((size_t)b*NPOINT + p)*128);
    float acc = b2[0];
    #pragma unroll 8
    for (int cq = 0; cq < 32; ++cq) {
        float4 xv = xb[cq];
        float4 wv = *(const float4*)(w2 + cq*4);
        float4 sc = *(const float4*)(bn1 + cq*4);
        float4 sh = *(const float4*)(bn1 + 128 + cq*4);
        acc = fmaf(wv.x, fmaxf(fmaf(xv.x, sc.x, sh.x), 0.0f), acc);
        acc = fmaf(wv.y, fmaxf(fmaf(xv.y, sc.y, sh.y), 0.0f), acc);
        acc = fmaf(wv.z, fmaxf(fmaf(xv.z, sc.z, sh.z), 0.0f), acc);
        acc = fmaf(wv.w, fmaxf(fmaf(xv.w, sc.w, sh.w), 0.0f), acc);
    }
    out[b*NPOINT + p] = acc;
}

extern "C" void kernel_launch(void* const* d_in, const int* in_sizes, int n_in,
                              void* d_out, int out_size, void* d_ws, size_t ws_size,
                              hipStream_t stream)
{
    const float* xyz   = (const float*)d_in[0];
    const float* ofeat = (const float*)d_in[1];
    const float* cand  = (const float*)d_in[2];
    /* d_in[3] = pred_cls, unused */
    const float* offs  = (const float*)d_in[4];
    const float* angc  = (const float*)d_in[5];
    const float* angr  = (const float*)d_in[6];
    const float* w1    = (const float*)d_in[7];
    const float* b1    = (const float*)d_in[8];
    const float* w2    = (const float*)d_in[9];
    const float* b2    = (const float*)d_in[10];
    const float* wi0   = (const float*)d_in[11];
    const float* bi0   = (const float*)d_in[12];
    const float* gi0   = (const float*)d_in[13];
    const float* bei0  = (const float*)d_in[14];
    const float* wi1   = (const float*)d_in[15];
    const float* bi1   = (const float*)d_in[16];
    const float* gi1   = (const float*)d_in[17];
    const float* bei1  = (const float*)d_in[18];
    const float* wi2   = (const float*)d_in[19];
    const float* bi2   = (const float*)d_in[20];

    char* ws = (char*)d_ws;
    float*  corners = (float*)(ws + OFF_CORNERS);
    float*  rel     = (float*)(ws + OFF_REL);
    int*    idx3    = (int*)  (ws + OFF_IDX3);
    float*  w3      = (float*)(ws + OFF_W3);
    float*  featT   = (float*)(ws + OFF_FEATT);
    float*  w1t     = (float*)(ws + OFF_W1T);
    float*  w2t     = (float*)(ws + OFF_W2T);
    float4* xyzp    = (float4*)(ws + OFF_XYZP);
    float*  h2      = (float*)(ws + OFF_H2);
    float*  x0      = (float*)(ws + OFF_X0);
    float*  x1      = (float*)(ws + OFF_X1);
    float*  bn0     = (float*)(ws + OFF_BN0);
    float*  bn1     = (float*)(ws + OFF_BN1);

    k_prep     <<<1168, 256, 0, stream>>>(cand, offs, angc, angr, w1, w2, ofeat, xyz,
                                          corners, rel, w1t, w2t, featT, xyzp);
    k_three_nn <<<512, 512, 0, stream>>>(xyzp, cand, offs, corners, idx3, w3);
    k_mlp      <<<256, 512, 0, stream>>>(idx3, w3, featT, rel,
                                         w1t, b1, w2t, b2, h2);
    k_head0    <<<128, 256, 0, stream>>>(h2, wi0, bi0, gi0, bei0, x0, bn0);
    k_head1    <<<128, 256, 0, stream>>>(x0, bn0, wi1, bi1, gi1, bei1, x1, bn1);
    k_final    <<<1, 256, 0, stream>>>(x1, bn1, wi2, bi2, (float*)d_out);
}

// Round 10
// 218.674 us; speedup vs baseline: 1.7344x; 1.0530x over previous
//
#include <hip/hip_runtime.h>
#include <math.h>

#define BSZ 2
#define NPOINT 128
#define NPTS 8192
#define CH_F 128
#define HEAD_BINS 12
#define KCOR 64
#define MTOT (NPOINT*KCOR)   /* 8192 corners per batch */
#define FEAT_C 131
#define MLP2_C 256

/* ---- workspace byte offsets (256-aligned) ---- */
#define OFF_CORNERS 0u          /* 196608 */
#define OFF_REL     196608u     /* 196608 */
#define OFF_IDX3    393216u     /* [2][8192][3] int = 196608 */
#define OFF_W3      589824u     /* [2][8192][3] f32 = 196608 */
#define OFF_FEATT   6684672u    /* [2][8192][128] = 8388608 */
#define OFF_W1T     15073280u   /* 67072 */
#define OFF_W2T     15140352u   /* 131072 */
#define OFF_XYZP    15271424u   /* [2][8192] float4 = 262144 */
#define OFF_H2      15533568u   /* [2][128][256] = 262144 */
#define OFF_X0      15795712u   /* [2][128][128] = 131072 */
#define OFF_X1      15926784u   /* 131072 */
#define OFF_BN0     16057856u   /* 1024 */
#define OFF_BN1     16058880u   /* 1024 */

/* ========== k_prep: decode (0..63) | w-transpose (64..79) | xyz-pack (80..143) | f-transpose (144..1167) ========== */
__global__ __launch_bounds__(256) void k_prep(const float* __restrict__ cand, const float* __restrict__ offs,
                        const float* __restrict__ angc, const float* __restrict__ angr,
                        const float* __restrict__ w1, const float* __restrict__ w2,
                        const float* __restrict__ of, const float* __restrict__ xyz,
                        float* __restrict__ corners, float* __restrict__ rel,
                        float* __restrict__ w1t, float* __restrict__ w2t,
                        float* __restrict__ ft, float4* __restrict__ xyzp)
{
    __shared__ float tile[128][17];
    __shared__ float sr[4*KCOR*3];
    __shared__ float sc_[4*KCOR*3];
    int bid = blockIdx.x;
    int t = threadIdx.x;
    if (bid < 64) {
        int b = bid >> 5, p0 = (bid & 31) * 4;
        int lb = t >> 6, k = t & 63;
        int bp = b*NPOINT + p0 + lb;
        const float* ac = angc + bp*HEAD_BINS;
        int best = 0; float bv = ac[0];
        #pragma unroll
        for (int j = 1; j < HEAD_BINS; ++j) { float v = ac[j]; if (v > bv) { bv = v; best = j; } }
        float ares = angr[bp*HEAD_BINS + best];
        float angle = (float)best * 0.52359877559829882f + ares;
        float heading = (angle > 3.14159265358979323f) ? (angle - 6.28318530717958647f) : angle;
        float cx = cand[bp*3+0] + offs[bp*6+0];
        float cy = cand[bp*3+1] + offs[bp*6+1];
        float cz = cand[bp*3+2] + offs[bp*6+2];
        float dl = fmaxf(offs[bp*6+3]*2.0f, 0.1f);
        float dw = fmaxf(offs[bp*6+4]*2.0f, 0.1f);
        float dh = fmaxf(offs[bp*6+5]*2.0f, 0.1f);
        float chd = cosf(heading), shd = sinf(heading);
        int ix = (k>>4)&3, iy = (k>>2)&3, iz = k&3;
        float gx = (ix==3) ? 1.0f : (-1.0f + (2.0f/3.0f)*(float)ix);
        float gy = (iy==3) ? 1.0f : (-1.0f + (2.0f/3.0f)*(float)iy);
        float gz = (iz==3) ? 1.0f : (-1.0f + (2.0f/3.0f)*(float)iz);
        float wx = gx*dl, wy = gy*dw, wz = gz*dh;
        float rx = wx*chd - wy*shd;
        float ry = wx*shd + wy*chd;
        int si = (lb*KCOR + k)*3;
        sr[si+0] = rx;      sr[si+1] = ry;      sr[si+2] = wz;
        sc_[si+0] = rx+cx;  sc_[si+1] = ry+cy;  sc_[si+2] = wz+cz;
        __syncthreads();
        size_t base = ((size_t)b*MTOT + (size_t)p0*KCOR)*3;
        if (t < 192) {
            ((float4*)(rel + base))[t]     = ((const float4*)sr)[t];
            ((float4*)(corners + base))[t] = ((const float4*)sc_)[t];
        }
    } else if (bid < 80) {
        int i0 = (bid-64)*256 + t;
        for (int i = i0; i < FEAT_C*128; i += 16*256) { int o = i & 127, c = i >> 7; w1t[i] = w1[o*FEAT_C + c]; }
        for (int i = i0; i < 128*256;    i += 16*256) { int o = i & 255, c = i >> 8; w2t[i] = w2[o*128 + c]; }
    } else if (bid < 144) {
        int i = (bid-80)*256 + t;          /* 0..16383 */
        const float* s = xyz + (size_t)i*3;
        float x = s[0], y = s[1], z = s[2];
        xyzp[i] = make_float4(x, y, z, (x*x + y*y) + z*z);
    } else {
        int bi = bid - 144;                /* 0..1023 */
        int b = bi >> 9;
        int n0 = (bi & 511) * 16;
        #pragma unroll
        for (int it = 0; it < 2; ++it) {
            int id = it*256 + t;
            int c = id >> 2, q = id & 3;
            float4 v = *(const float4*)(of + ((size_t)(b*CH_F + c))*NPTS + n0 + q*4);
            tile[c][q*4+0] = v.x; tile[c][q*4+1] = v.y; tile[c][q*4+2] = v.z; tile[c][q*4+3] = v.w;
        }
        __syncthreads();
        #pragma unroll
        for (int it = 0; it < 2; ++it) {
            int id = it*256 + t;
            int n = id >> 5, cq = id & 31;
            float4 o;
            o.x = tile[cq*4+0][n]; o.y = tile[cq*4+1][n]; o.z = tile[cq*4+2][n]; o.w = tile[cq*4+3][n];
            *(float4*)(ft + ((size_t)b*NPTS + n0 + n)*CH_F + cq*4) = o;
        }
    }
}

/* ========== three_nn: exact box-prefilter + LDS-tiled refine ==========
   block = (b, p, half): 32 corners of one box; 512 threads.
   Bound: any point in a corner's top-3 has d(p,center) <= r3(center) + 2H.  */
__global__ __launch_bounds__(512) void k_three_nn(const float4* __restrict__ xyzp,
        const float* __restrict__ cand, const float* __restrict__ offs,
        const float* __restrict__ corners,
        int* __restrict__ idx3, float* __restrict__ w3)
{
    __shared__ unsigned short lidx[NPTS];  /* candidate indices, 16 KB */
    __shared__ float4 ptile[512];          /* staged candidate points, 8 KB */
    __shared__ int    itile[512];          /* their indices, 2 KB */
    __shared__ float  red[1752];           /* top-3 reduce */
    __shared__ float  pms[512*3];
    __shared__ int    pmi[512*3];
    __shared__ int    s_cnt;
    __shared__ float  s_T;

    int bid = blockIdx.x;               /* 0..511 */
    int b    = bid >> 8;
    int p    = (bid >> 1) & 127;
    int half = bid & 1;
    int t = threadIdx.x;
    int bp = b*NPOINT + p;

    float cx = cand[bp*3+0] + offs[bp*6+0];
    float cy = cand[bp*3+1] + offs[bp*6+1];
    float cz = cand[bp*3+2] + offs[bp*6+2];
    float dl = fmaxf(offs[bp*6+3]*2.0f, 0.1f);
    float dw = fmaxf(offs[bp*6+4]*2.0f, 0.1f);
    float dh = fmaxf(offs[bp*6+5]*2.0f, 0.1f);
    float H  = sqrtf((dl*dl + dw*dw) + dh*dh);
    float scc = (cx*cx + cy*cy) + cz*cz;

    const float4* xb = xyzp + (size_t)b*NPTS;

    /* ---- pass 1: center distance, cache d2, per-thread top-3 ---- */
    float d2c[16];
    float a0 = 3.4e38f, a1 = 3.4e38f, a2 = 3.4e38f;
    #pragma unroll
    for (int i = 0; i < 16; ++i) {
        float4 P = xb[i*512 + t];
        float dot = fmaf(cz, P.z, fmaf(cy, P.y, cx*P.x));
        float d2 = (scc + P.w) - 2.0f*dot;
        d2c[i] = d2;
        a2 = __builtin_amdgcn_fmed3f(d2, a1, a2);
        a1 = __builtin_amdgcn_fmed3f(d2, a0, a1);
        a0 = fminf(d2, a0);
    }
    red[t*3+0] = a0; red[t*3+1] = a1; red[t*3+2] = a2;
    if (t == 0) s_cnt = 0;
    __syncthreads();
    if (t < 64) {
        float m0 = 3.4e38f, m1 = 3.4e38f, m2 = 3.4e38f;
        for (int s = t*8; s < t*8+8; ++s) {
            #pragma unroll
            for (int j = 0; j < 3; ++j) {
                float v = red[s*3+j];
                m2 = __builtin_amdgcn_fmed3f(v, m1, m2);
                m1 = __builtin_amdgcn_fmed3f(v, m0, m1);
                m0 = fminf(v, m0);
            }
        }
        red[1536 + t*3+0] = m0; red[1536 + t*3+1] = m1; red[1536 + t*3+2] = m2;
    }
    __syncthreads();
    if (t == 0) {
        float m0 = 3.4e38f, m1 = 3.4e38f, m2 = 3.4e38f;
        for (int s = 0; s < 64; ++s) {
            #pragma unroll
            for (int j = 0; j < 3; ++j) {
                float v = red[1536 + s*3+j];
                m2 = __builtin_amdgcn_fmed3f(v, m1, m2);
                m1 = __builtin_amdgcn_fmed3f(v, m0, m1);
                m0 = fminf(v, m0);
            }
        }
        float r3 = sqrtf(fmaxf(m2, 0.0f));
        float rad = r3 + 2.0f*H;
        s_T = rad*rad*1.0002f + 0.25f;   /* generous fp margin — exactness-safe */
    }
    __syncthreads();

    /* ---- pass 2: compact candidate indices ---- */
    float T = s_T;
    #pragma unroll
    for (int i = 0; i < 16; ++i) {
        if (d2c[i] <= T) {
            int pos = atomicAdd(&s_cnt, 1);
            lidx[pos] = (unsigned short)(i*512 + t);
        }
    }
    __syncthreads();
    int C = s_cnt;

    /* ---- pass 3: LDS-tiled refine: 32 corners x C candidates ---- */
    int ck  = half*32 + (t >> 4);        /* corner 0..63 within box */
    int sub = t & 15;
    size_t crow = (size_t)b*MTOT + p*KCOR + ck;
    float ox = corners[crow*3+0], oy = corners[crow*3+1], oz = corners[crow*3+2];
    float so = (ox*ox + oy*oy) + oz*oz;
    float s0 = 3.4e38f, s1 = 3.4e38f, s2 = 3.4e38f;
    int i0 = 0x7fffffff, i1 = 0x7fffffff, i2 = 0x7fffffff;

    int ntile = (C + 511) >> 9;
    for (int tb = 0; tb < ntile; ++tb) {
        __syncthreads();                 /* previous tile fully consumed */
        int j = (tb << 9) + t;
        if (j < C) {
            int idx = lidx[j];
            ptile[t] = xb[idx];          /* independent loads — pipelined */
            itile[t] = idx;
        } else {
            ptile[t] = make_float4(0.0f, 0.0f, 0.0f, 3.0e38f);  /* d2 ~ 3e38, finite */
            itile[t] = 0x7fffffff;
        }
        __syncthreads();
        #pragma unroll 4
        for (int k = sub; k < 512; k += 16) {   /* stride-16 float4: conflict-free */
            float4 P = ptile[k];
            int idx = itile[k];
            float dot = fmaf(oz, P.z, fmaf(oy, P.y, ox*P.x));
            float d2 = (so + P.w) - 2.0f*dot;   /* bit-identical to brute force */
            bool lt0 = (d2 < s0) || (d2 == s0 && idx < i0);
            bool lt1 = (d2 < s1) || (d2 == s1 && idx < i1);
            bool lt2 = (d2 < s2) || (d2 == s2 && idx < i2);
            s2 = lt1 ? s1 : (lt2 ? d2  : s2); i2 = lt1 ? i1 : (lt2 ? idx : i2);
            s1 = lt0 ? s0 : (lt1 ? d2  : s1); i1 = lt0 ? i0 : (lt1 ? idx : i1);
            s0 = lt0 ? d2 : s0;               i0 = lt0 ? idx : i0;
        }
    }
    pms[t*3+0] = s0; pms[t*3+1] = s1; pms[t*3+2] = s2;
    pmi[t*3+0] = i0; pmi[t*3+1] = i1; pmi[t*3+2] = i2;
    __syncthreads();

    /* ---- final merge (one lane per corner) + weights + store ---- */
    if (t < 32) {
        float f0 = 3.4e38f, f1 = 3.4e38f, f2 = 3.4e38f;
        int   j0 = 0x7fffffff, j1 = 0x7fffffff, j2 = 0x7fffffff;
        for (int tt = t*16; tt < t*16+16; ++tt) {
            #pragma unroll
            for (int j = 0; j < 3; ++j) {
                float d = pms[tt*3+j]; int id = pmi[tt*3+j];
                bool lt0 = (d < f0) || (d == f0 && id < j0);
                bool lt1 = (d < f1) || (d == f1 && id < j1);
                bool lt2 = (d < f2) || (d == f2 && id < j2);
                f2 = lt1 ? f1 : (lt2 ? d  : f2); j2 = lt1 ? j1 : (lt2 ? id : j2);
                f1 = lt0 ? f0 : (lt1 ? d  : f1); j1 = lt0 ? j0 : (lt1 ? id : j1);
                f0 = lt0 ? d  : f0;              j0 = lt0 ? id : j0;
            }
        }
        int ckf = half*32 + t;
        size_t row = (size_t)b*MTOT + p*KCOR + ckf;
        float qx = corners[row*3+0], qy = corners[row*3+1], qz = corners[row*3+2];
        int ii[3] = {j0, j1, j2};
        float w[3];
        #pragma unroll
        for (int j = 0; j < 3; ++j) {
            float4 P = xb[ii[j]];
            float dx = P.x - qx, dy = P.y - qy, dz = P.z - qz;
            float dist = sqrtf((dx*dx + dy*dy) + dz*dz);
            w[j] = 1.0f/(dist + 1e-8f);
        }
        float wsum = (w[0]+w[1])+w[2];
        #pragma unroll
        for (int j = 0; j < 3; ++j) {
            idx3[row*3+j] = ii[j];
            w3[row*3+j]   = w[j]/wsum;
        }
    }
}

/* ========== fused: gather-interp + MLP1 -> MLP2 -> maxpool per (b,p) ========== */
__global__ __launch_bounds__(512) void k_mlp(const int* __restrict__ idx3, const float* __restrict__ w3,
        const float* __restrict__ featT, const float* __restrict__ rel,
        const float* __restrict__ w1t, const float* __restrict__ b1,
        const float* __restrict__ w2t, const float* __restrict__ b2,
        float* __restrict__ h2)
{
    __shared__ float lds[FEAT_C*64];          /* [c][m], 33.5 KB */
    __shared__ float swt[3][64];
    __shared__ int   sidx[3][64];
    int blk = blockIdx.x; int b = blk >> 7, p = blk & 127;
    int t = threadIdx.x;
    int g0 = b*MTOT + p*KCOR;

    if (t < 64) {
        size_t row = (size_t)(g0 + t)*3;
        #pragma unroll
        for (int j = 0; j < 3; ++j) { sidx[j][t] = idx3[row+j]; swt[j][t] = w3[row+j]; }
    } else if (t < 256) {
        int u = t - 64;                        /* 0..191: rel rows 0..2 */
        lds[(u % 3)*64 + (u / 3)] = rel[(size_t)g0*3 + u];
    }
    __syncthreads();

    const float4* fb = (const float4*)(featT + (size_t)b*NPTS*CH_F);
    #pragma unroll
    for (int it = 0; it < 4; ++it) {
        int idx = it*512 + t;                  /* 0..2047 */
        int cq = idx >> 6, m = idx & 63;
        int j0 = sidx[0][m], j1 = sidx[1][m], j2 = sidx[2][m];
        float w0 = swt[0][m], w1 = swt[1][m], w2 = swt[2][m];
        float4 f0 = fb[(size_t)j0*32 + cq];
        float4 f1 = fb[(size_t)j1*32 + cq];
        float4 f2 = fb[(size_t)j2*32 + cq];
        float4 v;
        v.x = (f0.x*w0 + f1.x*w1) + f2.x*w2;
        v.y = (f0.y*w0 + f1.y*w1) + f2.y*w2;
        v.z = (f0.z*w0 + f1.z*w1) + f2.z*w2;
        v.w = (f0.w*w0 + f1.w*w1) + f2.w*w2;
        int c0 = 3 + cq*4;
        lds[(c0+0)*64+m] = v.x; lds[(c0+1)*64+m] = v.y;
        lds[(c0+2)*64+m] = v.z; lds[(c0+3)*64+m] = v.w;
    }
    __syncthreads();

    /* phase1: o = og*4+i (32 og), m = mg*4+j (16 mg) */
    int og = t >> 4, mg = t & 15;
    float acc[4][4];
    #pragma unroll
    for (int i = 0; i < 4; ++i) { float bb = b1[og*4+i];
        #pragma unroll
        for (int j = 0; j < 4; ++j) acc[i][j] = bb; }
    #pragma unroll 4
    for (int c = 0; c < FEAT_C; ++c) {
        float4 wv = *(const float4*)(w1t + c*128 + og*4);
        float4 f0 = *(const float4*)(&lds[c*64 + mg*4]);
        float fv[4] = {f0.x,f0.y,f0.z,f0.w};
        float wa[4] = {wv.x,wv.y,wv.z,wv.w};
        #pragma unroll
        for (int i = 0; i < 4; ++i)
            #pragma unroll
            for (int j = 0; j < 4; ++j)
                acc[i][j] = fmaf(wa[i], fv[j], acc[i][j]);
    }
    __syncthreads();
    #pragma unroll
    for (int i = 0; i < 4; ++i) {
        float4 r0 = make_float4(fmaxf(acc[i][0],0.f), fmaxf(acc[i][1],0.f), fmaxf(acc[i][2],0.f), fmaxf(acc[i][3],0.f));
        *(float4*)(&lds[(og*4+i)*64 + mg*4]) = r0;
    }
    __syncthreads();

    /* phase2: o = og2*4+i (64 og2), m = mg2*8+j (8 mg2) */
    int og2 = t >> 3, mg2 = t & 7;
    float a2[4][8];
    #pragma unroll
    for (int i = 0; i < 4; ++i) { float bb = b2[og2*4+i];
        #pragma unroll
        for (int j = 0; j < 8; ++j) a2[i][j] = bb; }
    #pragma unroll 2
    for (int c = 0; c < 128; ++c) {
        float4 wv = *(const float4*)(w2t + c*MLP2_C + og2*4);
        float4 f0 = *(const float4*)(&lds[c*64 + mg2*8]);
        float4 f1 = *(const float4*)(&lds[c*64 + mg2*8 + 4]);
        float fv[8] = {f0.x,f0.y,f0.z,f0.w,f1.x,f1.y,f1.z,f1.w};
        float wa[4] = {wv.x,wv.y,wv.z,wv.w};
        #pragma unroll
        for (int i = 0; i < 4; ++i)
            #pragma unroll
            for (int j = 0; j < 8; ++j)
                a2[i][j] = fmaf(wa[i], fv[j], a2[i][j]);
    }
    float mx[4];
    #pragma unroll
    for (int i = 0; i < 4; ++i) {
        float m0 = a2[i][0];
        #pragma unroll
        for (int j = 1; j < 8; ++j) m0 = fmaxf(m0, a2[i][j]);
        mx[i] = fmaxf(m0, 0.0f);
    }
    #pragma unroll
    for (int off = 1; off < 8; off <<= 1)
        #pragma unroll
        for (int i = 0; i < 4; ++i)
            mx[i] = fmaxf(mx[i], __shfl_xor(mx[i], off, 64));
    if (mg2 == 0)   /* h2 layout: [b][p][o] */
        *(float4*)(&h2[((size_t)b*NPOINT + p)*MLP2_C + og2*4]) = make_float4(mx[0],mx[1],mx[2],mx[3]);
}

/* ========== IoU head: gemm + BN stats fused; x layouts are [b][p][c] ========== */
__global__ __launch_bounds__(256) void k_head0(const float* __restrict__ h2, const float* __restrict__ w0,
                        const float* __restrict__ b0, const float* __restrict__ g0,
                        const float* __restrict__ be0,
                        float* __restrict__ x0, float* __restrict__ bn0)
{
    __shared__ float ssum[256], ssq[256];
    int o = blockIdx.x;            /* 0..127 */
    int t = threadIdx.x;           /* 256 = (b,p) */
    int b = t >> 7, p = t & 127;
    const float4* hb = (const float4*)(h2 + ((size_t)b*NPOINT + p)*MLP2_C);
    const float4* wr = (const float4*)(w0 + (size_t)o*MLP2_C);
    float acc = b0[o];
    #pragma unroll 8
    for (int cq = 0; cq < 64; ++cq) {
        float4 h = hb[cq], w = wr[cq];
        acc = fmaf(h.x, w.x, acc); acc = fmaf(h.y, w.y, acc);
        acc = fmaf(h.z, w.z, acc); acc = fmaf(h.w, w.w, acc);
    }
    x0[((size_t)b*NPOINT + p)*128 + o] = acc;
    ssum[t] = acc; ssq[t] = acc*acc;
    __syncthreads();
    if (t < 128) { ssum[t] += ssum[t+128]; ssq[t] += ssq[t+128]; }
    __syncthreads();
    if (t < 64) {
        float s = ssum[t] + ssum[t+64];
        float q = ssq[t] + ssq[t+64];
        #pragma unroll
        for (int off = 32; off >= 1; off >>= 1) {
            s += __shfl_down(s, off, 64);
            q += __shfl_down(q, off, 64);
        }
        if (t == 0) {
            float mean = s * (1.0f/256.0f);
            float var  = q * (1.0f/256.0f) - mean*mean;
            if (var < 0.f) var = 0.f;
            float scale = g0[o] / sqrtf(var + 1e-5f);
            bn0[o]       = scale;
            bn0[128 + o] = be0[o] - mean*scale;
        }
    }
}

__global__ __launch_bounds__(256) void k_head1(const float* __restrict__ x0, const float* __restrict__ bn0,
                        const float* __restrict__ w1, const float* __restrict__ b1,
                        const float* __restrict__ g1, const float* __restrict__ be1,
                        float* __restrict__ x1, float* __restrict__ bn1)
{
    __shared__ float ssum[256], ssq[256];
    int o = blockIdx.x;
    int t = threadIdx.x;
    int b = t >> 7, p = t & 127;
    const float4* xb = (const float4*)(x0 + ((size_t)b*NPOINT + p)*128);
    const float4* wr = (const float4*)(w1 + (size_t)o*128);
    float acc = b1[o];
    #pragma unroll 8
    for (int cq = 0; cq < 32; ++cq) {
        float4 xv = xb[cq], wv = wr[cq];
        float4 sc = *(const float4*)(bn0 + cq*4);
        float4 sh = *(const float4*)(bn0 + 128 + cq*4);
        acc = fmaf(wv.x, fmaxf(fmaf(xv.x, sc.x, sh.x), 0.0f), acc);
        acc = fmaf(wv.y, fmaxf(fmaf(xv.y, sc.y, sh.y), 0.0f), acc);
        acc = fmaf(wv.z, fmaxf(fmaf(xv.z, sc.z, sh.z), 0.0f), acc);
        acc = fmaf(wv.w, fmaxf(fmaf(xv.w, sc.w, sh.w), 0.0f), acc);
    }
    x1[((size_t)b*NPOINT + p)*128 + o] = acc;
    ssum[t] = acc; ssq[t] = acc*acc;
    __syncthreads();
    if (t < 128) { ssum[t] += ssum[t+128]; ssq[t] += ssq[t+128]; }
    __syncthreads();
    if (t < 64) {
        float s = ssum[t] + ssum[t+64];
        float q = ssq[t] + ssq[t+64];
        #pragma unroll
        for (int off = 32; off >= 1; off >>= 1) {
            s += __shfl_down(s, off, 64);
            q += __shfl_down(q, off, 64);
        }
        if (t == 0) {
            float mean = s * (1.0f/256.0f);
            float var  = q * (1.0f/256.0f) - mean*mean;
            if (var < 0.f) var = 0.f;
            float scale = g1[o] / sqrtf(var + 1e-5f);
            bn1[o]       = scale;
            bn1[128 + o] = be1[o] - mean*scale;
        }
    }
}

__global__ void k_final(const float* __restrict__ x1, const float* __restrict__ bn1,
                        const float* __restrict__ w2, const float* __restrict__ b2,
                        float* __restrict__ out)
{
    int t = threadIdx.x;  /* 256 */
    int b = t >> 7, p = t & 127;
    const float4* xb = (const float4*)(x1 + ((size_t)b*NPOINT + p)*128);
    float acc = b2[0];
    #pragma unroll 8
    for (int cq = 0; cq < 32; ++cq) {
        float4 xv = xb[cq];
        float4 wv = *(const float4*)(w2 + cq*4);
        float4 sc = *(const float4*)(bn1 + cq*4);
        float4 sh = *(const float4*)(bn1 + 128 + cq*4);
        acc = fmaf(wv.x, fmaxf(fmaf(xv.x, sc.x, sh.x), 0.0f), acc);
        acc = fmaf(wv.y, fmaxf(fmaf(xv.y, sc.y, sh.y), 0.0f), acc);
        acc = fmaf(wv.z, fmaxf(fmaf(xv.z, sc.z, sh.z), 0.0f), acc);
        acc = fmaf(wv.w, fmaxf(fmaf(xv.w, sc.w, sh.w), 0.0f), acc);
    }
    out[b*NPOINT + p] = acc;
}

extern "C" void kernel_launch(void* const* d_in, const int* in_sizes, int n_in,
                              void* d_out, int out_size, void* d_ws, size_t ws_size,
                              hipStream_t stream)
{
    const float* xyz   = (const float*)d_in[0];
    const float* ofeat = (const float*)d_in[1];
    const float* cand  = (const float*)d_in[2];
    /* d_in[3] = pred_cls, unused */
    const float* offs  = (const float*)d_in[4];
    const float* angc  = (const float*)d_in[5];
    const float* angr  = (const float*)d_in[6];
    const float* w1    = (const float*)d_in[7];
    const float* b1    = (const float*)d_in[8];
    const float* w2    = (const float*)d_in[9];
    const float* b2    = (const float*)d_in[10];
    const float* wi0   = (const float*)d_in[11];
    const float* bi0   = (const float*)d_in[12];
    const float* gi0   = (const float*)d_in[13];
    const float* bei0  = (const float*)d_in[14];
    const float* wi1   = (const float*)d_in[15];
    const float* bi1   = (const float*)d_in[16];
    const float* gi1   = (const float*)d_in[17];
    const float* bei1  = (const float*)d_in[18];
    const float* wi2   = (const float*)d_in[19];
    const float* bi2   = (const float*)d_in[20];

    char* ws = (char*)d_ws;
    float*  corners = (float*)(ws + OFF_CORNERS);
    float*  rel     = (float*)(ws + OFF_REL);
    int*    idx3    = (int*)  (ws + OFF_IDX3);
    float*  w3      = (float*)(ws + OFF_W3);
    float*  featT   = (float*)(ws + OFF_FEATT);
    float*  w1t     = (float*)(ws + OFF_W1T);
    float*  w2t     = (float*)(ws + OFF_W2T);
    float4* xyzp    = (float4*)(ws + OFF_XYZP);
    float*  h2      = (float*)(ws + OFF_H2);
    float*  x0      = (float*)(ws + OFF_X0);
    float*  x1      = (float*)(ws + OFF_X1);
    float*  bn0     = (float*)(ws + OFF_BN0);
    float*  bn1     = (float*)(ws + OFF_BN1);

    k_prep     <<<1168, 256, 0, stream>>>(cand, offs, angc, angr, w1, w2, ofeat, xyz,
                                          corners, rel, w1t, w2t, featT, xyzp);
    k_three_nn <<<512, 512, 0, stream>>>(xyzp, cand, offs, corners, idx3, w3);
    k_mlp      <<<256, 512, 0, stream>>>(idx3, w3, featT, rel,
                                         w1t, b1, w2t, b2, h2);
    k_head0    <<<128, 256, 0, stream>>>(h2, wi0, bi0, gi0, bei0, x0, bn0);
    k_head1    <<<128, 256, 0, stream>>>(x0, bn0, wi1, bi1, gi1, bei1, x1, bn1);
    k_final    <<<1, 256, 0, stream>>>(x1, bn1, wi2, bi2, (float*)d_out);
}